// Round 6
// baseline (459.767 us; speedup 1.0000x reference)
//
#include <hip/hip_runtime.h>

namespace {

constexpr int HD  = 128;      // hidden dim
constexpr int NE  = 600000;   // edges per direction
constexpr int NDR = 200000;   // drugs
constexpr int NDI = 100000;   // diseases
constexpr int NB  = 8192;     // link batch

typedef __attribute__((ext_vector_type(8))) short short8;   // 8 bf16 in 4 VGPRs
typedef __attribute__((ext_vector_type(4))) float f32x4;

// ---- split-bf16 helpers: x = hi + lo (truncated), ~16 mantissa bits total ----
__device__ inline void splitf(float x, unsigned short& h, unsigned short& l) {
  unsigned u = __float_as_uint(x);
  h = (unsigned short)(u >> 16);
  float r = x - __uint_as_float(u & 0xffff0000u);   // exact residual
  l = (unsigned short)(__float_as_uint(r) >> 16);
}
__device__ inline void split4(const float4& v, uint2& ph, uint2& pl) {
  unsigned ux = __float_as_uint(v.x), uy = __float_as_uint(v.y);
  unsigned uz = __float_as_uint(v.z), uw = __float_as_uint(v.w);
  ph.x = (ux >> 16) | (uy & 0xffff0000u);
  ph.y = (uz >> 16) | (uw & 0xffff0000u);
  float rx = v.x - __uint_as_float(ux & 0xffff0000u);
  float ry = v.y - __uint_as_float(uy & 0xffff0000u);
  float rz = v.z - __uint_as_float(uz & 0xffff0000u);
  float rw = v.w - __uint_as_float(uw & 0xffff0000u);
  pl.x = (__float_as_uint(rx) >> 16) | (__float_as_uint(ry) & 0xffff0000u);
  pl.y = (__float_as_uint(rz) >> 16) | (__float_as_uint(rw) & 0xffff0000u);
}
// load 8 contiguous f32 and split into hi/lo bf16 fragments in-register
__device__ inline void split8(const float* p, short8& h8, short8& l8) {
  float4 v0 = *reinterpret_cast<const float4*>(p);
  float4 v1 = *reinterpret_cast<const float4*>(p + 4);
  uint2 h0, l0, h1, l1;
  split4(v0, h0, l0);
  split4(v1, h1, l1);
  union { unsigned u[4]; short8 s; } uh, ul;
  uh.u[0] = h0.x; uh.u[1] = h0.y; uh.u[2] = h1.x; uh.u[3] = h1.y;
  ul.u[0] = l0.x; ul.u[1] = l0.y; ul.u[2] = l1.x; ul.u[3] = l1.y;
  h8 = uh.s; l8 = ul.s;
}

// ---- MFMA B-fragment swizzled W layout ----
// Tile = 16 n-rows x 32 k. Element (n,k) -> tile*512 + quad(k)*128 + (n&15)*8 + (k&7),
// so a wave's B-fragment load is base + lane*8 (fully coalesced 1KB).
__device__ inline size_t swzW(int n, int k, int K) {
  return ((size_t)((n >> 4) * (K >> 5) + (k >> 5))) * 512 +
         (size_t)(((k >> 3) & 3) * 128 + (n & 15) * 8 + (k & 7));
}

// ---------------- batch flag + demand flag for batch nodes ----------------
__global__ void batch_mark(const int* __restrict__ drug_idx, const int* __restrict__ dis_idx,
                           unsigned char* __restrict__ fb_drug, unsigned char* __restrict__ fb_dis,
                           unsigned char* __restrict__ fd_drug, unsigned char* __restrict__ fd_dis) {
  int i = blockIdx.x * 256 + threadIdx.x;
  if (i < NB) { int g = drug_idx[i]; fb_drug[g] = 1; fd_drug[g] = 1; }
  else if (i < 2 * NB) { int g = dis_idx[i - NB]; fb_dis[g] = 1; fd_dis[g] = 1; }
}

// ---------------- edge-parallel demand mark: src of edges into batch dst ----------------
__global__ void edge_mark(const int* __restrict__ s0, const int* __restrict__ d0,   // d2di
                          const int* __restrict__ s1, const int* __restrict__ d1,   // di2dr
                          const unsigned char* __restrict__ fb_dis,
                          const unsigned char* __restrict__ fb_drug,
                          unsigned char* __restrict__ fd_drug, unsigned char* __restrict__ fd_dis) {
  int e = blockIdx.x * 256 + threadIdx.x;
  if (e >= NE) return;
  if (blockIdx.y == 0) { if (fb_dis[d0[e]]) fd_drug[s0[e]] = 1; }
  else                 { if (fb_drug[d1[e]]) fd_dis[s1[e]] = 1; }
}

// ---------------- filtered degree counts (demanded dst only) ----------------
__global__ void count_f(const int* __restrict__ d0, const int* __restrict__ d1,
                        const unsigned char* __restrict__ fd_dis,
                        const unsigned char* __restrict__ fd_drug,
                        int* __restrict__ c0, int* __restrict__ c1) {
  int e = blockIdx.x * 256 + threadIdx.x;
  if (e >= NE) return;
  if (blockIdx.y == 0) { int d = d0[e]; if (fd_dis[d]) atomicAdd(&c0[d], 1); }
  else                 { int d = d1[e]; if (fd_drug[d]) atomicAdd(&c1[d], 1); }
}

// ---------------- 3-phase exclusive scan, y selects dis/drug ----------------
__global__ void scan1y(const int* __restrict__ in0, int n0_, int* __restrict__ out0, int* __restrict__ bs0,
                       const int* __restrict__ in1, int n1_, int* __restrict__ out1, int* __restrict__ bs1) {
  const int* in; int n; int* outp; int* bs;
  if (blockIdx.y == 0) { in = in0; n = n0_; outp = out0; bs = bs0; }
  else                 { in = in1; n = n1_; outp = out1; bs = bs1; }
  if (blockIdx.x * 1024 >= n) return;
  __shared__ int s[256];
  int t = threadIdx.x;
  int idx = blockIdx.x * 1024 + t * 4;
  int4 v = make_int4(0, 0, 0, 0);
  if (idx + 3 < n) v = *reinterpret_cast<const int4*>(in + idx);
  else {
    if (idx     < n) v.x = in[idx];
    if (idx + 1 < n) v.y = in[idx + 1];
    if (idx + 2 < n) v.z = in[idx + 2];
    if (idx + 3 < n) v.w = in[idx + 3];
  }
  int tsum = v.x + v.y + v.z + v.w;
  s[t] = tsum;
  __syncthreads();
  for (int o = 1; o < 256; o <<= 1) {
    int x = (t >= o) ? s[t - o] : 0;
    __syncthreads();
    s[t] += x;
    __syncthreads();
  }
  int excl = s[t] - tsum;
  if (idx     < n) outp[idx]     = excl;
  if (idx + 1 < n) outp[idx + 1] = excl + v.x;
  if (idx + 2 < n) outp[idx + 2] = excl + v.x + v.y;
  if (idx + 3 < n) outp[idx + 3] = excl + v.x + v.y + v.z;
  if (t == 255) bs[blockIdx.x] = s[255];
}

__global__ void scan2(int* __restrict__ bs0, int nb0, int* __restrict__ bs1, int nb1) {
  int* bsum = (blockIdx.x == 0) ? bs0 : bs1;
  int nb = (blockIdx.x == 0) ? nb0 : nb1;
  __shared__ int s[256];
  int t = threadIdx.x;
  int v = (t < nb) ? bsum[t] : 0;
  s[t] = v;
  __syncthreads();
  for (int o = 1; o < 256; o <<= 1) {
    int x = (t >= o) ? s[t - o] : 0;
    __syncthreads();
    s[t] += x;
    __syncthreads();
  }
  if (t < nb) bsum[t] = s[t] - v;
}

__global__ void scan3y(int* __restrict__ out0, int n0_, const int* __restrict__ bs0,
                       int* __restrict__ out1, int n1_, const int* __restrict__ bs1) {
  int* outp; int n; const int* bs;
  if (blockIdx.y == 0) { outp = out0; n = n0_; bs = bs0; }
  else                 { outp = out1; n = n1_; bs = bs1; }
  int i = blockIdx.x * 256 + threadIdx.x;
  if (i < n) outp[i] += bs[i >> 10];
}

// ---------------- filtered CSR bucket scatter ----------------
__global__ void csr_f(const int* __restrict__ s0, const int* __restrict__ d0,
                      const int* __restrict__ s1, const int* __restrict__ d1, int nE,
                      const unsigned char* __restrict__ fd_dis,
                      const unsigned char* __restrict__ fd_drug,
                      const int* __restrict__ off0, int* __restrict__ cur0, int* __restrict__ csr0,
                      const int* __restrict__ off1, int* __restrict__ cur1, int* __restrict__ csr1) {
  int e = blockIdx.x * 256 + threadIdx.x;
  if (e >= nE) return;
  if (blockIdx.y == 0) {
    int d = d0[e];
    if (fd_dis[d]) csr0[off0[d] + atomicAdd(&cur0[d], 1)] = s0[e];
  } else {
    int d = d1[e];
    if (fd_drug[d]) csr1[off1[d] + atomicAdd(&cur1[d], 1)] = s1[e];
  }
}

// ---------------- demand flags -> list, ONE atomic per 1024-thread block ----------------
__global__ __launch_bounds__(1024) void compact_list(
    const unsigned char* __restrict__ f0, int n0_, int* __restrict__ l0, int* __restrict__ c0,
    const unsigned char* __restrict__ f1, int n1_, int* __restrict__ l1, int* __restrict__ c1) {
  const unsigned char* f; int n; int *l, *c;
  if (blockIdx.y == 0) { f = f0; n = n0_; l = l0; c = c0; }
  else                 { f = f1; n = n1_; l = l1; c = c1; }
  __shared__ int wsum[16];
  __shared__ int sbase;
  int i = blockIdx.x * 1024 + threadIdx.x;
  int wid = threadIdx.x >> 6, lane = threadIdx.x & 63;
  bool dem = (i < n) && f[i];
  unsigned long long mask = __ballot(dem);
  int before = __popcll(mask & ((1ull << lane) - 1ull));
  int wtot = __popcll(mask);
  if (lane == 0) wsum[wid] = wtot;
  __syncthreads();
  if (threadIdx.x == 0) {
    int t = 0;
#pragma unroll
    for (int w = 0; w < 16; ++w) { int v = wsum[w]; wsum[w] = t; t += v; }
    sbase = t ? atomicAdd(c, t) : 0;
  }
  __syncthreads();
  if (dem) l[sbase + wsum[wid] + before] = i;
}

// ---------------- L0 gather (paired, y=direction, GRID-STRIDE): f32 in, split mean out ----
// Output rows are NODE-indexed (agg buffers are full-node-sized).
__global__ void gather_f2s(const float* __restrict__ x0, const int* __restrict__ csr0,
                           const int* __restrict__ off0, const int* __restrict__ cnt0,
                           const int* __restrict__ list0, const int* __restrict__ n0Dev,
                           unsigned short* __restrict__ oh0, unsigned short* __restrict__ ol0,
                           const float* __restrict__ x1, const int* __restrict__ csr1,
                           const int* __restrict__ off1, const int* __restrict__ cnt1,
                           const int* __restrict__ list1, const int* __restrict__ n1Dev,
                           unsigned short* __restrict__ oh1, unsigned short* __restrict__ ol1) {
  const float* x; const int *csr, *offp, *cnt, *list, *nDev;
  unsigned short *oh, *ol;
  if (blockIdx.y == 0) { x = x0; csr = csr0; offp = off0; cnt = cnt0; list = list0; nDev = n0Dev; oh = oh0; ol = ol0; }
  else                 { x = x1; csr = csr1; offp = off1; cnt = cnt1; list = list1; nDev = n1Dev; oh = oh1; ol = ol1; }
  const int nRows = *nDev;
  const int c = threadIdx.x & 31;
  for (int r = blockIdx.x * 8 + (threadIdx.x >> 5); r < nRows; r += gridDim.x * 8) {
    int g = list[r];
    int o = offp[g], n = cnt[g];
    float4 acc = make_float4(0.f, 0.f, 0.f, 0.f);
    int j = 0;
    for (; j + 4 <= n; j += 4) {
      int s0 = csr[o + j], s1 = csr[o + j + 1], s2 = csr[o + j + 2], s3 = csr[o + j + 3];
      float4 v0 = reinterpret_cast<const float4*>(x + (size_t)s0 * HD)[c];
      float4 v1 = reinterpret_cast<const float4*>(x + (size_t)s1 * HD)[c];
      float4 v2 = reinterpret_cast<const float4*>(x + (size_t)s2 * HD)[c];
      float4 v3 = reinterpret_cast<const float4*>(x + (size_t)s3 * HD)[c];
      acc.x += v0.x; acc.y += v0.y; acc.z += v0.z; acc.w += v0.w;
      acc.x += v1.x; acc.y += v1.y; acc.z += v1.z; acc.w += v1.w;
      acc.x += v2.x; acc.y += v2.y; acc.z += v2.z; acc.w += v2.w;
      acc.x += v3.x; acc.y += v3.y; acc.z += v3.z; acc.w += v3.w;
    }
    for (; j < n; ++j) {
      int s = csr[o + j];
      float4 v = reinterpret_cast<const float4*>(x + (size_t)s * HD)[c];
      acc.x += v.x; acc.y += v.y; acc.z += v.z; acc.w += v.w;
    }
    float inv = 1.0f / (float)max(n, 1);
    float4 m = make_float4(acc.x * inv, acc.y * inv, acc.z * inv, acc.w * inv);
    uint2 ph, pl;
    split4(m, ph, pl);
    reinterpret_cast<uint2*>(oh + (size_t)g * HD)[c] = ph;
    reinterpret_cast<uint2*>(ol + (size_t)g * HD)[c] = pl;
  }
}

// ---------------- merged weight prep: split_weights + fold(attn->MLP1) in one dispatch ------
__global__ void prep_weights(const float* __restrict__ Wl, const float* __restrict__ Wr,
                             const float* __restrict__ W2,
                             unsigned short* __restrict__ WLh, unsigned short* __restrict__ WLl,
                             unsigned short* __restrict__ WRh, unsigned short* __restrict__ WRl,
                             unsigned short* __restrict__ W2h, unsigned short* __restrict__ W2l,
                             const float* __restrict__ W1, const float* __restrict__ b1,
                             const float* __restrict__ attn_Win, const float* __restrict__ attn_bin,
                             const float* __restrict__ attn_Wout, const float* __restrict__ attn_bout,
                             unsigned short* __restrict__ Ah, unsigned short* __restrict__ Al,
                             unsigned short* __restrict__ Bh, unsigned short* __restrict__ Bl,
                             float* __restrict__ bc) {
  __shared__ float tA[2][128], tB[2][128];
  const int b = blockIdx.x;
  if (b < 512) {
    const int widx[6] = {0, 1, 3, 4, 5, 6};
    int i = b * 256 + threadIdx.x;
    if (i < 98304) {
      int m = i >> 14, e = i & 16383;
      int n = e >> 7, k = e & 127;
      size_t o = (size_t)m * 16384 + swzW(n, k, 128);
      splitf(Wl[(size_t)widx[m] * 16384 + e], WLh[o], WLl[o]);
      splitf(Wr[(size_t)widx[m] * 16384 + e], WRh[o], WRl[o]);
    } else if (i < 131072) {
      int j = i - 98304;
      int n = j >> 8, k = j & 255;
      size_t o = swzW(n, k, 256);
      splitf(W2[j], W2h[o], W2l[o]);
    }
    return;
  }
  // fold path: 128 blocks x (2 rows of 128 threads)
  const int sub = threadIdx.x >> 7, k = threadIdx.x & 127;
  const int r = (b - 512) * 2 + sub;
  const float* w1r = W1 + (size_t)r * 512;
  const float* Wout0 = attn_Wout;                 // module 0: drug_att <- dis_emb
  const float* Wout1 = attn_Wout + HD * HD;       // module 1: dis_att  <- drug_emb
  float ta = 0.0f, tb = 0.0f;
  for (int m = 0; m < HD; ++m) {
    ta += w1r[384 + m] * Wout1[m * HD + k];
    tb += w1r[256 + m] * Wout0[m * HD + k];
  }
  tA[sub][k] = ta; tB[sub][k] = tb;
  __syncthreads();
  const float* Wv0 = attn_Win + 2 * HD * HD;               // module 0 Wv
  const float* Wv1 = attn_Win + 3 * HD * HD + 2 * HD * HD; // module 1 Wv
  float accA = 0.0f, accB = 0.0f;
  for (int u = 0; u < HD; ++u) {
    accA += tA[sub][u] * Wv1[u * HD + k];
    accB += tB[sub][u] * Wv0[u * HD + k];
  }
  size_t o = swzW(r, k, 128);
  splitf(w1r[k] + accA, Ah[o], Al[o]);
  splitf(w1r[128 + k] + accB, Bh[o], Bl[o]);
  if (k == 0) {
    const float* bv0 = attn_bin + 2 * HD;
    const float* bv1 = attn_bin + 3 * HD + 2 * HD;
    float bb = b1[r];
    for (int m = 0; m < HD; ++m)
      bb += w1r[256 + m] * attn_bout[m] + w1r[384 + m] * attn_bout[HD + m];
    for (int u = 0; u < HD; ++u) bb += tB[sub][u] * bv0[u] + tA[sub][u] * bv1[u];
    bc[r] = bb;
  }
}

// ---------------- L0 dual GEMM (round-1 proven body): LDS-staged X1 + X2, 2-phase ----------
// C = relu( agg @ Wa + emb_self @ Wb + bias ), split-bf16 out.
struct L0Args {
  const unsigned short* X1h; const unsigned short* X1l;  // split agg (NODE-indexed)
  const float* x2f32;                                    // self emb table (f32)
  const int* rowNode;   // row -> node id (batch idx array, or demand list)
  const unsigned short* Wah; const unsigned short* Wal;  // swizzled Wl
  const unsigned short* Wbh; const unsigned short* Wbl;  // swizzled Wr
  const float* bias;
  const int* nRowsDev;                                   // nullptr -> NB
  unsigned short* Oh; unsigned short* Ol;
};

template <bool OBN>   // OBN: write outputs at node rows (list GEMMs) vs linear rows (batch)
__device__ inline void l0_body(const L0Args& A, int bx, int tid) {
  // LDS: 64 rows x 64-k chunk, +8 ushort pad -> row stride 144B (16B aligned, 2-way banks = free)
  __shared__ unsigned short sX1h[64][72];
  __shared__ unsigned short sX1l[64][72];
  __shared__ unsigned short sX2h[64][72];
  __shared__ unsigned short sX2l[64][72];

  const int nRows = A.nRowsDev ? *A.nRowsDev : NB;
  const int row0 = bx * 64;
  if (row0 >= nRows) return;
  const int lane = tid & 63;
  const int wv = tid >> 6;
  const int quad = lane >> 4, m16 = lane & 15;
  const int n0 = wv * 32;

  // staging role: 4 threads per row, 16 elements each
  const int sr = tid >> 2;
  const int sk = (tid & 3) * 16;
  int gsrc = row0 + sr;
  if (gsrc > nRows - 1) gsrc = nRows - 1;
  const int node = A.rowNode[gsrc];

  f32x4 acc[4][2];
#pragma unroll
  for (int ct = 0; ct < 2; ++ct) {
    float b = A.bias[n0 + ct * 16 + m16];
    f32x4 bb = {b, b, b, b};
#pragma unroll
    for (int rt = 0; rt < 4; ++rt) acc[rt][ct] = bb;
  }

  for (int kc = 0; kc < HD; kc += 64) {
    // ---- stage X1 chunk (split bf16, node-indexed) ----
    {
      const unsigned short* p = A.X1h + (size_t)node * HD + kc + sk;
      *reinterpret_cast<short8*>(&sX1h[sr][sk])     = *reinterpret_cast<const short8*>(p);
      *reinterpret_cast<short8*>(&sX1h[sr][sk + 8]) = *reinterpret_cast<const short8*>(p + 8);
      const unsigned short* q = A.X1l + (size_t)node * HD + kc + sk;
      *reinterpret_cast<short8*>(&sX1l[sr][sk])     = *reinterpret_cast<const short8*>(q);
      *reinterpret_cast<short8*>(&sX1l[sr][sk + 8]) = *reinterpret_cast<const short8*>(q + 8);
    }
    // ---- stage X2 chunk (f32 emb -> in-register split), coalesced 4 thr/row ----
    {
      const float* p = A.x2f32 + (size_t)node * HD + kc + sk;
      short8 h0, l0, h1, l1;
      split8(p, h0, l0);
      split8(p + 8, h1, l1);
      *reinterpret_cast<short8*>(&sX2h[sr][sk])     = h0;
      *reinterpret_cast<short8*>(&sX2h[sr][sk + 8]) = h1;
      *reinterpret_cast<short8*>(&sX2l[sr][sk])     = l0;
      *reinterpret_cast<short8*>(&sX2l[sr][sk + 8]) = l1;
    }
    __syncthreads();

    // ---- compute: 2 MFMA k-steps per chunk ----
#pragma unroll
    for (int kk = 0; kk < 64; kk += 32) {
      const int ktile = (kc + kk) >> 5;
      short8 bah[2], bal[2], bbh[2], bbl[2];
#pragma unroll
      for (int ct = 0; ct < 2; ++ct) {
        size_t wo = ((size_t)(((n0 + ct * 16) >> 4) * 4 + ktile)) * 512 + (size_t)lane * 8;
        bah[ct] = *reinterpret_cast<const short8*>(A.Wah + wo);
        bal[ct] = *reinterpret_cast<const short8*>(A.Wal + wo);
        bbh[ct] = *reinterpret_cast<const short8*>(A.Wbh + wo);
        bbl[ct] = *reinterpret_cast<const short8*>(A.Wbl + wo);
      }
#pragma unroll
      for (int rt = 0; rt < 4; ++rt) {
        const int xr = rt * 16 + m16;
        const int xo = kk + quad * 8;
        short8 a1h = *reinterpret_cast<const short8*>(&sX1h[xr][xo]);
        short8 a1l = *reinterpret_cast<const short8*>(&sX1l[xr][xo]);
#pragma unroll
        for (int ct = 0; ct < 2; ++ct) {
          acc[rt][ct] = __builtin_amdgcn_mfma_f32_16x16x32_bf16(a1h, bah[ct], acc[rt][ct], 0, 0, 0);
          acc[rt][ct] = __builtin_amdgcn_mfma_f32_16x16x32_bf16(a1h, bal[ct], acc[rt][ct], 0, 0, 0);
          acc[rt][ct] = __builtin_amdgcn_mfma_f32_16x16x32_bf16(a1l, bah[ct], acc[rt][ct], 0, 0, 0);
        }
        short8 a2h = *reinterpret_cast<const short8*>(&sX2h[xr][xo]);
        short8 a2l = *reinterpret_cast<const short8*>(&sX2l[xr][xo]);
#pragma unroll
        for (int ct = 0; ct < 2; ++ct) {
          acc[rt][ct] = __builtin_amdgcn_mfma_f32_16x16x32_bf16(a2h, bbh[ct], acc[rt][ct], 0, 0, 0);
          acc[rt][ct] = __builtin_amdgcn_mfma_f32_16x16x32_bf16(a2h, bbl[ct], acc[rt][ct], 0, 0, 0);
          acc[rt][ct] = __builtin_amdgcn_mfma_f32_16x16x32_bf16(a2l, bbh[ct], acc[rt][ct], 0, 0, 0);
        }
      }
    }
    __syncthreads();
  }

  // epilogue: relu + split, D[m = quad*4+i][n = m16] per 16x16 tile
#pragma unroll
  for (int rt = 0; rt < 4; ++rt) {
#pragma unroll
    for (int i = 0; i < 4; ++i) {
      int m = row0 + rt * 16 + quad * 4 + i;
      if (m < nRows) {
        const int orow = OBN ? A.rowNode[m] : m;
#pragma unroll
        for (int ct = 0; ct < 2; ++ct) {
          float v = fmaxf(acc[rt][ct][i], 0.0f);
          size_t o = (size_t)orow * HD + n0 + ct * 16 + m16;
          unsigned short h, l;
          splitf(v, h, l);
          A.Oh[o] = h; A.Ol[o] = l;
        }
      }
    }
  }
}

// all four L0 GEMMs (2 batch + 2 list), grid-stride over virtual blocks.
// min-waves/EU=4 caps VGPR at 128 -> 4 waves/SIMD (round-1 body fit in 124).
__global__ __launch_bounds__(256, 4) void l0_quad(L0Args a, L0Args b, L0Args c, L0Args d) {
  const int nA = NB / 64, nB2 = NB / 64;
  const int nc = (*c.nRowsDev + 63) >> 6;
  const int nd = (*d.nRowsDev + 63) >> 6;
  const int total = nA + nB2 + nc + nd;
  for (int vb = blockIdx.x; vb < total; vb += gridDim.x) {
    if (vb < nA)                 l0_body<false>(a, vb, threadIdx.x);
    else if (vb < nA + nB2)      l0_body<false>(b, vb - nA, threadIdx.x);
    else if (vb < nA + nB2 + nc) l0_body<true>(c, vb - nA - nB2, threadIdx.x);
    else                         l0_body<true>(d, vb - nA - nB2 - nc, threadIdx.x);
  }
}

// ---------------- fused batch tail: L1 gather + L1 dual pair -> MLP1 -> MLP2 -> dot ----
__global__ __launch_bounds__(256) void tail_fused(
    const unsigned short* __restrict__ tgDh, const unsigned short* __restrict__ tgDl,  // tg_dis (node rows)
    const unsigned short* __restrict__ tgRh, const unsigned short* __restrict__ tgRl,  // tg_drug
    const int* __restrict__ drug_idx, const int* __restrict__ dis_idx,
    const int* __restrict__ csrA, const int* __restrict__ offA, const int* __restrict__ cntA,  // di2dr
    const int* __restrict__ csrB, const int* __restrict__ offB, const int* __restrict__ cntB,  // d2di
    const unsigned short* __restrict__ dXh, const unsigned short* __restrict__ dXl,    // d1b (batch rows)
    const unsigned short* __restrict__ dYh, const unsigned short* __restrict__ dYl,    // s1b
    const unsigned short* __restrict__ WLah, const unsigned short* __restrict__ WLal,
    const unsigned short* __restrict__ WRah, const unsigned short* __restrict__ WRal,
    const unsigned short* __restrict__ WLbh, const unsigned short* __restrict__ WLbl,
    const unsigned short* __restrict__ WRbh, const unsigned short* __restrict__ WRbl,
    const float* __restrict__ biasA, const float* __restrict__ biasB,
    const unsigned short* __restrict__ Amh, const unsigned short* __restrict__ Aml,
    const unsigned short* __restrict__ Bmh, const unsigned short* __restrict__ Bml,
    const float* __restrict__ bc,
    const unsigned short* __restrict__ W2h, const unsigned short* __restrict__ W2l,
    const float* __restrict__ b2, const float* __restrict__ W3,
    const float* __restrict__ b3, float* __restrict__ out) {
  __shared__ unsigned short sA0h[32][136], sA0l[32][136];   // L1 agg (drug side)
  __shared__ unsigned short sA1h[32][136], sA1l[32][136];   // L1 agg (disease side)
  __shared__ unsigned short sX2h[32][72], sX2l[32][72];
  __shared__ unsigned short sP0h[32][136], sP0l[32][136], sP1h[32][136], sP1l[32][136];
  __shared__ float sRed[32][4];

  const int tid = threadIdx.x;
  const int lane = tid & 63, wv = tid >> 6;
  const int quad = lane >> 4, m16 = lane & 15;
  const int n0 = wv * 32;
  const int row0 = blockIdx.x * 32;
  const int sr = tid >> 3, sk = (tid & 7) * 8;     // 8 thr/row, one short8 each
  const size_t grow = (size_t)(row0 + sr) * HD;

  // ---- phase 0: L1 mean aggregation into LDS (exact gather_s2s numerics) ----
  {
    const int c = tid & 31;
    for (int rr = tid >> 5; rr < 32; rr += 8) {
      const int row = row0 + rr;
#pragma unroll
      for (int side = 0; side < 2; ++side) {
        const int node = side ? dis_idx[row] : drug_idx[row];
        const int* csr = side ? csrB : csrA;
        const int o = side ? offB[node] : offA[node];
        const int n = side ? cntB[node] : cntA[node];
        const unsigned short* xh = side ? tgRh : tgDh;
        const unsigned short* xl = side ? tgRl : tgDl;
        float4 acc = make_float4(0.f, 0.f, 0.f, 0.f);
        auto accum = [&](uint2 hh, uint2 ll) {
          acc.x += __uint_as_float(hh.x << 16) + __uint_as_float(ll.x << 16);
          acc.y += __uint_as_float(hh.x & 0xffff0000u) + __uint_as_float(ll.x & 0xffff0000u);
          acc.z += __uint_as_float(hh.y << 16) + __uint_as_float(ll.y << 16);
          acc.w += __uint_as_float(hh.y & 0xffff0000u) + __uint_as_float(ll.y & 0xffff0000u);
        };
        int j = 0;
        for (; j + 4 <= n; j += 4) {
          int p0 = csr[o + j], p1 = csr[o + j + 1], p2 = csr[o + j + 2], p3 = csr[o + j + 3];
          uint2 h0 = reinterpret_cast<const uint2*>(xh + (size_t)p0 * HD)[c];
          uint2 l0 = reinterpret_cast<const uint2*>(xl + (size_t)p0 * HD)[c];
          uint2 h1 = reinterpret_cast<const uint2*>(xh + (size_t)p1 * HD)[c];
          uint2 l1 = reinterpret_cast<const uint2*>(xl + (size_t)p1 * HD)[c];
          uint2 h2 = reinterpret_cast<const uint2*>(xh + (size_t)p2 * HD)[c];
          uint2 l2 = reinterpret_cast<const uint2*>(xl + (size_t)p2 * HD)[c];
          uint2 h3 = reinterpret_cast<const uint2*>(xh + (size_t)p3 * HD)[c];
          uint2 l3 = reinterpret_cast<const uint2*>(xl + (size_t)p3 * HD)[c];
          accum(h0, l0); accum(h1, l1); accum(h2, l2); accum(h3, l3);
        }
        for (; j < n; ++j) {
          int p = csr[o + j];
          uint2 hh = reinterpret_cast<const uint2*>(xh + (size_t)p * HD)[c];
          uint2 ll = reinterpret_cast<const uint2*>(xl + (size_t)p * HD)[c];
          accum(hh, ll);
        }
        float inv = 1.0f / (float)max(n, 1);
        float4 m = make_float4(acc.x * inv, acc.y * inv, acc.z * inv, acc.w * inv);
        uint2 ph, pl;
        split4(m, ph, pl);
        if (side) {
          *reinterpret_cast<uint2*>(&sA1h[rr][c * 4]) = ph;
          *reinterpret_cast<uint2*>(&sA1l[rr][c * 4]) = pl;
        } else {
          *reinterpret_cast<uint2*>(&sA0h[rr][c * 4]) = ph;
          *reinterpret_cast<uint2*>(&sA0l[rr][c * 4]) = pl;
        }
      }
    }
  }

  // ---- stage 1: two dual 32x128 L1 GEMMs -> de (sP0), se (sP1), relu+split ----
  for (int half = 0; half < 2; ++half) {
    const unsigned short (*A1h)[136] = half ? sA1h : sA0h;
    const unsigned short (*A1l)[136] = half ? sA1l : sA0l;
    const unsigned short* X2h = half ? dYh : dXh;
    const unsigned short* X2l = half ? dYl : dXl;
    const unsigned short* Wah = half ? WLbh : WLah;
    const unsigned short* Wal = half ? WLbl : WLal;
    const unsigned short* Wbh = half ? WRbh : WRah;
    const unsigned short* Wbl = half ? WRbl : WRal;
    const float* bias = half ? biasB : biasA;

    f32x4 acc[2][2];
#pragma unroll
    for (int ct = 0; ct < 2; ++ct) {
      float b = bias[n0 + ct * 16 + m16];
      f32x4 bb = {b, b, b, b};
      acc[0][ct] = bb; acc[1][ct] = bb;
    }

    for (int kc = 0; kc < HD; kc += 64) {
      __syncthreads();   // guards phase-0 completion (first iter) / prior sX2 reads
      *reinterpret_cast<short8*>(&sX2h[sr][sk]) = *reinterpret_cast<const short8*>(X2h + grow + kc + sk);
      *reinterpret_cast<short8*>(&sX2l[sr][sk]) = *reinterpret_cast<const short8*>(X2l + grow + kc + sk);
      __syncthreads();
#pragma unroll
      for (int kk = 0; kk < 64; kk += 32) {
        const int ktile = (kc + kk) >> 5;
        short8 bah[2], bal[2], bbh[2], bbl[2];
#pragma unroll
        for (int ct = 0; ct < 2; ++ct) {
          size_t wo = ((size_t)(((n0 + ct * 16) >> 4) * 4 + ktile)) * 512 + (size_t)lane * 8;
          bah[ct] = *reinterpret_cast<const short8*>(Wah + wo);
          bal[ct] = *reinterpret_cast<const short8*>(Wal + wo);
          bbh[ct] = *reinterpret_cast<const short8*>(Wbh + wo);
          bbl[ct] = *reinterpret_cast<const short8*>(Wbl + wo);
        }
#pragma unroll
        for (int rt = 0; rt < 2; ++rt) {
          const int xr = rt * 16 + m16;
          const int x1o = kc + kk + quad * 8;
          const int x2o = kk + quad * 8;
          short8 a1h = *reinterpret_cast<const short8*>(&A1h[xr][x1o]);
          short8 a1l = *reinterpret_cast<const short8*>(&A1l[xr][x1o]);
#pragma unroll
          for (int ct = 0; ct < 2; ++ct) {
            acc[rt][ct] = __builtin_amdgcn_mfma_f32_16x16x32_bf16(a1h, bah[ct], acc[rt][ct], 0, 0, 0);
            acc[rt][ct] = __builtin_amdgcn_mfma_f32_16x16x32_bf16(a1h, bal[ct], acc[rt][ct], 0, 0, 0);
            acc[rt][ct] = __builtin_amdgcn_mfma_f32_16x16x32_bf16(a1l, bah[ct], acc[rt][ct], 0, 0, 0);
          }
          short8 a2h = *reinterpret_cast<const short8*>(&sX2h[xr][x2o]);
          short8 a2l = *reinterpret_cast<const short8*>(&sX2l[xr][x2o]);
#pragma unroll
          for (int ct = 0; ct < 2; ++ct) {
            acc[rt][ct] = __builtin_amdgcn_mfma_f32_16x16x32_bf16(a2h, bbh[ct], acc[rt][ct], 0, 0, 0);
            acc[rt][ct] = __builtin_amdgcn_mfma_f32_16x16x32_bf16(a2h, bbl[ct], acc[rt][ct], 0, 0, 0);
            acc[rt][ct] = __builtin_amdgcn_mfma_f32_16x16x32_bf16(a2l, bbh[ct], acc[rt][ct], 0, 0, 0);
          }
        }
      }
    }
    // epilogue -> LDS (relu + split); sP not read until after next sync
    unsigned short (*dh)[136] = half ? sP1h : sP0h;
    unsigned short (*dl)[136] = half ? sP1l : sP0l;
#pragma unroll
    for (int rt = 0; rt < 2; ++rt)
#pragma unroll
      for (int ct = 0; ct < 2; ++ct)
#pragma unroll
        for (int i = 0; i < 4; ++i) {
          float v = fmaxf(acc[rt][ct][i], 0.0f);
          unsigned short h, l;
          splitf(v, h, l);
          dh[rt * 16 + quad * 4 + i][n0 + ct * 16 + m16] = h;
          dl[rt * 16 + quad * 4 + i][n0 + ct * 16 + m16] = l;
        }
  }
  __syncthreads();

  // ---- MLP1: h1[32x256] = relu(de@Am + se@Bm + bc) ----
  f32x4 acc1[2][4];
#pragma unroll
  for (int ct = 0; ct < 4; ++ct) {
    const int nc_ = (ct < 2) ? (n0 + ct * 16) : (128 + n0 + (ct - 2) * 16);
    float b = bc[nc_ + m16];
    f32x4 bb = {b, b, b, b};
    acc1[0][ct] = bb; acc1[1][ct] = bb;
  }
#pragma unroll
  for (int kt = 0; kt < 4; ++kt) {
    const int xo = kt * 32 + quad * 8;
    short8 adh[2], adl[2], ash[2], asl[2];
#pragma unroll
    for (int rt = 0; rt < 2; ++rt) {
      const int xr = rt * 16 + m16;
      adh[rt] = *reinterpret_cast<const short8*>(&sP0h[xr][xo]);
      adl[rt] = *reinterpret_cast<const short8*>(&sP0l[xr][xo]);
      ash[rt] = *reinterpret_cast<const short8*>(&sP1h[xr][xo]);
      asl[rt] = *reinterpret_cast<const short8*>(&sP1l[xr][xo]);
    }
#pragma unroll
    for (int ct = 0; ct < 4; ++ct) {
      const int nc_ = (ct < 2) ? (n0 + ct * 16) : (128 + n0 + (ct - 2) * 16);
      size_t wo = ((size_t)((nc_ >> 4) * 4 + kt)) * 512 + (size_t)lane * 8;
      short8 wah = *reinterpret_cast<const short8*>(Amh + wo);
      short8 wal = *reinterpret_cast<const short8*>(Aml + wo);
      short8 wbh = *reinterpret_cast<const short8*>(Bmh + wo);
      short8 wbl = *reinterpret_cast<const short8*>(Bml + wo);
#pragma unroll
      for (int rt = 0; rt < 2; ++rt) {
        acc1[rt][ct] = __builtin_amdgcn_mfma_f32_16x16x32_bf16(adh[rt], wah, acc1[rt][ct], 0, 0, 0);
        acc1[rt][ct] = __builtin_amdgcn_mfma_f32_16x16x32_bf16(adh[rt], wal, acc1[rt][ct], 0, 0, 0);
        acc1[rt][ct] = __builtin_amdgcn_mfma_f32_16x16x32_bf16(adl[rt], wah, acc1[rt][ct], 0, 0, 0);
        acc1[rt][ct] = __builtin_amdgcn_mfma_f32_16x16x32_bf16(ash[rt], wbh, acc1[rt][ct], 0, 0, 0);
        acc1[rt][ct] = __builtin_amdgcn_mfma_f32_16x16x32_bf16(ash[rt], wbl, acc1[rt][ct], 0, 0, 0);
        acc1[rt][ct] = __builtin_amdgcn_mfma_f32_16x16x32_bf16(asl[rt], wbh, acc1[rt][ct], 0, 0, 0);
      }
    }
  }
  __syncthreads();   // all de/se reads done; reuse sP for h1
#pragma unroll
  for (int ct = 0; ct < 4; ++ct)
#pragma unroll
    for (int rt = 0; rt < 2; ++rt)
#pragma unroll
      for (int i = 0; i < 4; ++i) {
        float v = fmaxf(acc1[rt][ct][i], 0.0f);
        unsigned short h, l;
        splitf(v, h, l);
        const int rr = rt * 16 + quad * 4 + i;
        if (ct < 2) {
          const int cc = n0 + ct * 16 + m16;
          sP0h[rr][cc] = h; sP0l[rr][cc] = l;
        } else {
          const int cc = n0 + (ct - 2) * 16 + m16;
          sP1h[rr][cc] = h; sP1l[rr][cc] = l;
        }
      }
  __syncthreads();

  // ---- MLP2: h2[32x128] = relu(h1@W2 + b2), K=256 from sP0 (k<128) and sP1 (k>=128) ----
  f32x4 acc2[2][2];
#pragma unroll
  for (int ct = 0; ct < 2; ++ct) {
    float b = b2[n0 + ct * 16 + m16];
    f32x4 bb = {b, b, b, b};
    acc2[0][ct] = bb; acc2[1][ct] = bb;
  }
#pragma unroll
  for (int kt = 0; kt < 8; ++kt) {
    const unsigned short (*ph)[136] = (kt < 4) ? sP0h : sP1h;
    const unsigned short (*pl)[136] = (kt < 4) ? sP0l : sP1l;
    const int xo = (kt & 3) * 32 + quad * 8;
    short8 ah[2], al[2];
#pragma unroll
    for (int rt = 0; rt < 2; ++rt) {
      const int xr = rt * 16 + m16;
      ah[rt] = *reinterpret_cast<const short8*>(&ph[xr][xo]);
      al[rt] = *reinterpret_cast<const short8*>(&pl[xr][xo]);
    }
#pragma unroll
    for (int ct = 0; ct < 2; ++ct) {
      size_t wo = ((size_t)(((n0 + ct * 16) >> 4) * 8 + kt)) * 512 + (size_t)lane * 8;
      short8 wh = *reinterpret_cast<const short8*>(W2h + wo);
      short8 wl = *reinterpret_cast<const short8*>(W2l + wo);
#pragma unroll
      for (int rt = 0; rt < 2; ++rt) {
        acc2[rt][ct] = __builtin_amdgcn_mfma_f32_16x16x32_bf16(ah[rt], wh, acc2[rt][ct], 0, 0, 0);
        acc2[rt][ct] = __builtin_amdgcn_mfma_f32_16x16x32_bf16(ah[rt], wl, acc2[rt][ct], 0, 0, 0);
        acc2[rt][ct] = __builtin_amdgcn_mfma_f32_16x16x32_bf16(al[rt], wh, acc2[rt][ct], 0, 0, 0);
      }
    }
  }

  // ---- final dot with W3 (relu on h2 in-register) ----
  const float w3a = W3[n0 + m16];
  const float w3b = W3[n0 + 16 + m16];
#pragma unroll
  for (int rt = 0; rt < 2; ++rt)
#pragma unroll
    for (int i = 0; i < 4; ++i) {
      float p = fmaxf(acc2[rt][0][i], 0.0f) * w3a + fmaxf(acc2[rt][1][i], 0.0f) * w3b;
      p += __shfl_xor(p, 1);
      p += __shfl_xor(p, 2);
      p += __shfl_xor(p, 4);
      p += __shfl_xor(p, 8);
      if (m16 == 0) sRed[rt * 16 + quad * 4 + i][wv] = p;
    }
  __syncthreads();
  if (tid < 32)
    out[row0 + tid] = sRed[tid][0] + sRed[tid][1] + sRed[tid][2] + sRed[tid][3] + b3[0];
}

}  // namespace

extern "C" void kernel_launch(void* const* d_in, const int* in_sizes, int n_in,
                              void* d_out, int out_size, void* d_ws, size_t ws_size,
                              hipStream_t stream) {
  const int* src_d2di  = (const int*)d_in[0];
  const int* dst_d2di  = (const int*)d_in[1];
  const int* src_di2dr = (const int*)d_in[2];
  const int* dst_di2dr = (const int*)d_in[3];
  const int* drug_idx  = (const int*)d_in[4];
  const int* dis_idx   = (const int*)d_in[5];
  const float* emb_drug = (const float*)d_in[6];
  const float* emb_dis  = (const float*)d_in[7];
  const float* Wl = (const float*)d_in[8];
  const float* bl = (const float*)d_in[9];
  const float* Wr = (const float*)d_in[10];
  const float* attn_Win  = (const float*)d_in[11];
  const float* attn_bin  = (const float*)d_in[12];
  const float* attn_Wout = (const float*)d_in[13];
  const float* attn_bout = (const float*)d_in[14];
  const float* W1 = (const float*)d_in[15];
  const float* b1 = (const float*)d_in[16];
  const float* W2 = (const float*)d_in[17];
  const float* b2 = (const float*)d_in[18];
  const float* W3 = (const float*)d_in[19];
  const float* b3 = (const float*)d_in[20];
  float* out = (float*)d_out;

  // ---- workspace carve (16B-aligned float units) ----
  float* ws = (float*)d_ws;
  size_t off = 0;
  auto carve = [&](size_t nfloats) {
    float* p = ws + off;
    off += (nfloats + 3) & ~(size_t)3;
    return p;
  };
  auto carveU = [&](size_t nush) { return (unsigned short*)carve((nush + 1) / 2); };

  // zeroed region (one memset): cnt/cursor ints + uchar flags + nctr
  int* cnt_dis     = (int*)carve(NDI);
  int* cnt_drug    = (int*)carve(NDR);
  int* cursor_dis  = (int*)carve(NDI);
  int* cursor_drug = (int*)carve(NDR);
  unsigned char* fb_dis  = (unsigned char*)carve((NDI + 3) / 4);
  unsigned char* fb_drug = (unsigned char*)carve((NDR + 3) / 4);
  unsigned char* fd_dis  = (unsigned char*)carve((NDI + 3) / 4);
  unsigned char* fd_drug = (unsigned char*)carve((NDR + 3) / 4);
  int* nctr        = (int*)carve(8);  // [0]=n_list_dis, [1]=n_list_drug
  const size_t zero_bytes = off * sizeof(float);
  // not zeroed
  int* off_dis   = (int*)carve(NDI);
  int* off_drug  = (int*)carve(NDR);
  int* list_dis  = (int*)carve(NDI);
  int* list_drug = (int*)carve(NDR);
  int* csr_d2di  = (int*)carve(NE);
  int* csr_di2dr = (int*)carve(NE);
  int* bsum_dis  = (int*)carve(256);
  int* bsum_drug = (int*)carve(256);

  // big split-bf16 buffers (NODE-indexed)
  unsigned short* aggh_dis  = carveU((size_t)NDI * HD);  // L0 mean agg
  unsigned short* aggl_dis  = carveU((size_t)NDI * HD);
  unsigned short* aggh_drug = carveU((size_t)NDR * HD);
  unsigned short* aggl_drug = carveU((size_t)NDR * HD);
  unsigned short* tgh_dis   = carveU((size_t)NDI * HD);  // L0 transformed (dis1_s0)
  unsigned short* tgl_dis   = carveU((size_t)NDI * HD);
  unsigned short* tgh_drug  = carveU((size_t)NDR * HD);  // L0 transformed (drug1_s1)
  unsigned short* tgl_drug  = carveU((size_t)NDR * HD);
  // batch-sized split buffers
  unsigned short* d1bh = carveU((size_t)NB * HD);  // drug1 (stack0) at batch rows
  unsigned short* d1bl = carveU((size_t)NB * HD);
  unsigned short* s1bh = carveU((size_t)NB * HD);  // dis1 (stack1) at batch rows
  unsigned short* s1bl = carveU((size_t)NB * HD);
  // weights (split, B-fragment swizzled)
  unsigned short* WLh = carveU(6 * 16384);
  unsigned short* WLl = carveU(6 * 16384);
  unsigned short* WRh = carveU(6 * 16384);
  unsigned short* WRl = carveU(6 * 16384);
  unsigned short* W2h = carveU(32768);
  unsigned short* W2l = carveU(32768);
  unsigned short* Amh = carveU(32768);
  unsigned short* Aml = carveU(32768);
  unsigned short* Bmh = carveU(32768);
  unsigned short* Bml = carveU(32768);
  // f32 small
  float* bc = carve(2 * HD);

  dim3 blk(256);
  const size_t WS = 16384;  // one 128x128 weight slot (elements)
  const int EB = (NE + 255) / 256;

  hipMemsetAsync(cnt_dis, 0, zero_bytes, stream);

  // weight prep (merged split + fold; independent of graph work)
  prep_weights<<<640, blk, 0, stream>>>(Wl, Wr, W2, WLh, WLl, WRh, WRl, W2h, W2l,
                                        W1, b1, attn_Win, attn_bin, attn_Wout, attn_bout,
                                        Amh, Aml, Bmh, Bml, bc);

  // demand marking (edge-parallel)
  batch_mark<<<(2 * NB + 255) / 256, blk, 0, stream>>>(drug_idx, dis_idx, fb_drug, fb_dis, fd_drug, fd_dis);
  edge_mark<<<dim3(EB, 2), blk, 0, stream>>>(src_d2di, dst_d2di, src_di2dr, dst_di2dr,
                                             fb_dis, fb_drug, fd_drug, fd_dis);

  // filtered degree counts; demand lists (1 atomic per 1024-thread block)
  count_f<<<dim3(EB, 2), blk, 0, stream>>>(dst_d2di, dst_di2dr, fd_dis, fd_drug, cnt_dis, cnt_drug);
  compact_list<<<dim3((NDR + 1023) / 1024, 2), dim3(1024), 0, stream>>>(
      fd_dis, NDI, list_dis, nctr + 0, fd_drug, NDR, list_drug, nctr + 1);

  // CSR offsets via deterministic 3-phase scan (filtered counts)
  scan1y<<<dim3((NDR + 1023) / 1024, 2), blk, 0, stream>>>(cnt_dis, NDI, off_dis, bsum_dis,
                                                           cnt_drug, NDR, off_drug, bsum_drug);
  scan2<<<2, blk, 0, stream>>>(bsum_dis, (NDI + 1023) / 1024, bsum_drug, (NDR + 1023) / 1024);
  scan3y<<<dim3((NDR + 255) / 256, 2), blk, 0, stream>>>(off_dis, NDI, bsum_dis, off_drug, NDR, bsum_drug);

  // filtered CSR scatter
  csr_f<<<dim3(EB, 2), blk, 0, stream>>>(src_d2di, dst_d2di, src_di2dr, dst_di2dr, NE,
                                         fd_dis, fd_drug,
                                         off_dis, cursor_dis, csr_d2di,
                                         off_drug, cursor_drug, csr_di2dr);

  // layer-0 mean aggregation at NODE rows (grid-stride, both directions)
  gather_f2s<<<dim3(1024, 2), blk, 0, stream>>>(
      emb_drug, csr_d2di, off_dis, cnt_dis, list_dis, nctr + 0, aggh_dis, aggl_dis,
      emb_dis, csr_di2dr, off_drug, cnt_drug, list_drug, nctr + 1, aggh_drug, aggl_drug);

  // all four L0 GEMMs in one grid-stride dispatch:
  //   a: dis1b (stack1, slot3) at batch rows; b: drug1b (stack0, slot1) at batch rows
  //   c: dis1_s0 (slot0) over list -> tg_dis (node rows)
  //   d: drug1_s1 (slot4) over list -> tg_drug (node rows)
  {
    L0Args z{};
    auto mk = [&](const unsigned short* X1h_, const unsigned short* X1l_, const float* x2_,
                  const int* rowNode_,
                  const unsigned short* Wah_, const unsigned short* Wal_,
                  const unsigned short* Wbh_, const unsigned short* Wbl_,
                  const float* bias_, const int* nDev,
                  unsigned short* Oh_, unsigned short* Ol_) {
      L0Args g = z;
      g.X1h = X1h_; g.X1l = X1l_; g.x2f32 = x2_;
      g.rowNode = rowNode_;
      g.Wah = Wah_; g.Wal = Wal_; g.Wbh = Wbh_; g.Wbl = Wbl_;
      g.bias = bias_; g.nRowsDev = nDev; g.Oh = Oh_; g.Ol = Ol_;
      return g;
    };
    L0Args a = mk(aggh_dis, aggl_dis, emb_dis, dis_idx,
                  WLh + 3 * WS, WLl + 3 * WS, WRh + 3 * WS, WRl + 3 * WS, bl + 4 * HD,
                  nullptr, s1bh, s1bl);
    L0Args b = mk(aggh_drug, aggl_drug, emb_drug, drug_idx,
                  WLh + 1 * WS, WLl + 1 * WS, WRh + 1 * WS, WRl + 1 * WS, bl + 1 * HD,
                  nullptr, d1bh, d1bl);
    L0Args c = mk(aggh_dis, aggl_dis, emb_dis, list_dis,
                  WLh + 0 * WS, WLl + 0 * WS, WRh + 0 * WS, WRl + 0 * WS, bl + 0 * HD,
                  nctr + 0, tgh_dis, tgl_dis);
    L0Args d = mk(aggh_drug, aggl_drug, emb_drug, list_drug,
                  WLh + 4 * WS, WLl + 4 * WS, WRh + 4 * WS, WRl + 4 * WS, bl + 5 * HD,
                  nctr + 1, tgh_drug, tgl_drug);
    l0_quad<<<2048, blk, 0, stream>>>(a, b, c, d);
  }

  // fused batch tail: L1 gather (LDS) + L1 pair (slots 2/5) -> MLP1 -> MLP2 -> dot(W3)
  tail_fused<<<NB / 32, blk, 0, stream>>>(
      tgh_dis, tgl_dis, tgh_drug, tgl_drug,
      drug_idx, dis_idx,
      csr_di2dr, off_drug, cnt_drug,
      csr_d2di, off_dis, cnt_dis,
      d1bh, d1bl, s1bh, s1bl,
      WLh + 2 * WS, WLl + 2 * WS, WRh + 2 * WS, WRl + 2 * WS,
      WLh + 5 * WS, WLl + 5 * WS, WRh + 5 * WS, WRl + 5 * WS,
      bl + 3 * HD, bl + 6 * HD,
      Amh, Aml, Bmh, Bml, bc, W2h, W2l, b2, W3, b3, out);

  (void)in_sizes; (void)n_in; (void)out_size; (void)ws_size;
}

// Round 7
// 456.788 us; speedup vs baseline: 1.0065x; 1.0065x over previous
//
#include <hip/hip_runtime.h>

namespace {

constexpr int HD  = 128;      // hidden dim
constexpr int NE  = 600000;   // edges per direction
constexpr int NDR = 200000;   // drugs
constexpr int NDI = 100000;   // diseases
constexpr int NB  = 8192;     // link batch

typedef __attribute__((ext_vector_type(8))) short short8;   // 8 bf16 in 4 VGPRs
typedef __attribute__((ext_vector_type(4))) float f32x4;

// ---- split-bf16 helpers: x = hi + lo (truncated), ~16 mantissa bits total ----
__device__ inline void splitf(float x, unsigned short& h, unsigned short& l) {
  unsigned u = __float_as_uint(x);
  h = (unsigned short)(u >> 16);
  float r = x - __uint_as_float(u & 0xffff0000u);   // exact residual
  l = (unsigned short)(__float_as_uint(r) >> 16);
}
__device__ inline void split4(const float4& v, uint2& ph, uint2& pl) {
  unsigned ux = __float_as_uint(v.x), uy = __float_as_uint(v.y);
  unsigned uz = __float_as_uint(v.z), uw = __float_as_uint(v.w);
  ph.x = (ux >> 16) | (uy & 0xffff0000u);
  ph.y = (uz >> 16) | (uw & 0xffff0000u);
  float rx = v.x - __uint_as_float(ux & 0xffff0000u);
  float ry = v.y - __uint_as_float(uy & 0xffff0000u);
  float rz = v.z - __uint_as_float(uz & 0xffff0000u);
  float rw = v.w - __uint_as_float(uw & 0xffff0000u);
  pl.x = (__float_as_uint(rx) >> 16) | (__float_as_uint(ry) & 0xffff0000u);
  pl.y = (__float_as_uint(rz) >> 16) | (__float_as_uint(rw) & 0xffff0000u);
}
// load 8 contiguous f32 and split into hi/lo bf16 fragments in-register
__device__ inline void split8(const float* p, short8& h8, short8& l8) {
  float4 v0 = *reinterpret_cast<const float4*>(p);
  float4 v1 = *reinterpret_cast<const float4*>(p + 4);
  uint2 h0, l0, h1, l1;
  split4(v0, h0, l0);
  split4(v1, h1, l1);
  union { unsigned u[4]; short8 s; } uh, ul;
  uh.u[0] = h0.x; uh.u[1] = h0.y; uh.u[2] = h1.x; uh.u[3] = h1.y;
  ul.u[0] = l0.x; ul.u[1] = l0.y; ul.u[2] = l1.x; ul.u[3] = l1.y;
  h8 = uh.s; l8 = ul.s;
}

// ---- MFMA B-fragment swizzled W layout ----
// Tile = 16 n-rows x 32 k. Element (n,k) -> tile*512 + quad(k)*128 + (n&15)*8 + (k&7),
// so a wave's B-fragment load is base + lane*8 (fully coalesced 1KB).
__device__ inline size_t swzW(int n, int k, int K) {
  return ((size_t)((n >> 4) * (K >> 5) + (k >> 5))) * 512 +
         (size_t)(((k >> 3) & 3) * 128 + (n & 15) * 8 + (k & 7));
}

// ---------------- batch flag + demand flag for batch nodes ----------------
__global__ void batch_mark(const int* __restrict__ drug_idx, const int* __restrict__ dis_idx,
                           unsigned char* __restrict__ fb_drug, unsigned char* __restrict__ fb_dis,
                           unsigned char* __restrict__ fd_drug, unsigned char* __restrict__ fd_dis) {
  int i = blockIdx.x * 256 + threadIdx.x;
  if (i < NB) { int g = drug_idx[i]; fb_drug[g] = 1; fd_drug[g] = 1; }
  else if (i < 2 * NB) { int g = dis_idx[i - NB]; fb_dis[g] = 1; fd_dis[g] = 1; }
}

// ---------------- edge-parallel demand mark: src of edges into batch dst ----------------
__global__ void edge_mark(const int* __restrict__ s0, const int* __restrict__ d0,   // d2di
                          const int* __restrict__ s1, const int* __restrict__ d1,   // di2dr
                          const unsigned char* __restrict__ fb_dis,
                          const unsigned char* __restrict__ fb_drug,
                          unsigned char* __restrict__ fd_drug, unsigned char* __restrict__ fd_dis) {
  int e = blockIdx.x * 256 + threadIdx.x;
  if (e >= NE) return;
  if (blockIdx.y == 0) { if (fb_dis[d0[e]]) fd_drug[s0[e]] = 1; }
  else                 { if (fb_drug[d1[e]]) fd_dis[s1[e]] = 1; }
}

// ---------------- filtered degree counts (demanded dst only) ----------------
__global__ void count_f(const int* __restrict__ d0, const int* __restrict__ d1,
                        const unsigned char* __restrict__ fd_dis,
                        const unsigned char* __restrict__ fd_drug,
                        int* __restrict__ c0, int* __restrict__ c1) {
  int e = blockIdx.x * 256 + threadIdx.x;
  if (e >= NE) return;
  if (blockIdx.y == 0) { int d = d0[e]; if (fd_dis[d]) atomicAdd(&c0[d], 1); }
  else                 { int d = d1[e]; if (fd_drug[d]) atomicAdd(&c1[d], 1); }
}

// ---------------- 3-phase exclusive scan, y selects dis/drug ----------------
__global__ void scan1y(const int* __restrict__ in0, int n0_, int* __restrict__ out0, int* __restrict__ bs0,
                       const int* __restrict__ in1, int n1_, int* __restrict__ out1, int* __restrict__ bs1) {
  const int* in; int n; int* outp; int* bs;
  if (blockIdx.y == 0) { in = in0; n = n0_; outp = out0; bs = bs0; }
  else                 { in = in1; n = n1_; outp = out1; bs = bs1; }
  if (blockIdx.x * 1024 >= n) return;
  __shared__ int s[256];
  int t = threadIdx.x;
  int idx = blockIdx.x * 1024 + t * 4;
  int4 v = make_int4(0, 0, 0, 0);
  if (idx + 3 < n) v = *reinterpret_cast<const int4*>(in + idx);
  else {
    if (idx     < n) v.x = in[idx];
    if (idx + 1 < n) v.y = in[idx + 1];
    if (idx + 2 < n) v.z = in[idx + 2];
    if (idx + 3 < n) v.w = in[idx + 3];
  }
  int tsum = v.x + v.y + v.z + v.w;
  s[t] = tsum;
  __syncthreads();
  for (int o = 1; o < 256; o <<= 1) {
    int x = (t >= o) ? s[t - o] : 0;
    __syncthreads();
    s[t] += x;
    __syncthreads();
  }
  int excl = s[t] - tsum;
  if (idx     < n) outp[idx]     = excl;
  if (idx + 1 < n) outp[idx + 1] = excl + v.x;
  if (idx + 2 < n) outp[idx + 2] = excl + v.x + v.y;
  if (idx + 3 < n) outp[idx + 3] = excl + v.x + v.y + v.z;
  if (t == 255) bs[blockIdx.x] = s[255];
}

__global__ void scan2(int* __restrict__ bs0, int nb0, int* __restrict__ bs1, int nb1) {
  int* bsum = (blockIdx.x == 0) ? bs0 : bs1;
  int nb = (blockIdx.x == 0) ? nb0 : nb1;
  __shared__ int s[256];
  int t = threadIdx.x;
  int v = (t < nb) ? bsum[t] : 0;
  s[t] = v;
  __syncthreads();
  for (int o = 1; o < 256; o <<= 1) {
    int x = (t >= o) ? s[t - o] : 0;
    __syncthreads();
    s[t] += x;
    __syncthreads();
  }
  if (t < nb) bsum[t] = s[t] - v;
}

__global__ void scan3y(int* __restrict__ out0, int n0_, const int* __restrict__ bs0,
                       int* __restrict__ out1, int n1_, const int* __restrict__ bs1) {
  int* outp; int n; const int* bs;
  if (blockIdx.y == 0) { outp = out0; n = n0_; bs = bs0; }
  else                 { outp = out1; n = n1_; bs = bs1; }
  int i = blockIdx.x * 256 + threadIdx.x;
  if (i < n) outp[i] += bs[i >> 10];
}

// ---------------- filtered CSR bucket scatter ----------------
__global__ void csr_f(const int* __restrict__ s0, const int* __restrict__ d0,
                      const int* __restrict__ s1, const int* __restrict__ d1, int nE,
                      const unsigned char* __restrict__ fd_dis,
                      const unsigned char* __restrict__ fd_drug,
                      const int* __restrict__ off0, int* __restrict__ cur0, int* __restrict__ csr0,
                      const int* __restrict__ off1, int* __restrict__ cur1, int* __restrict__ csr1) {
  int e = blockIdx.x * 256 + threadIdx.x;
  if (e >= nE) return;
  if (blockIdx.y == 0) {
    int d = d0[e];
    if (fd_dis[d]) csr0[off0[d] + atomicAdd(&cur0[d], 1)] = s0[e];
  } else {
    int d = d1[e];
    if (fd_drug[d]) csr1[off1[d] + atomicAdd(&cur1[d], 1)] = s1[e];
  }
}

// ---------------- demand flags -> list, ONE atomic per 1024-thread block ----------------
__global__ __launch_bounds__(1024) void compact_list(
    const unsigned char* __restrict__ f0, int n0_, int* __restrict__ l0, int* __restrict__ c0,
    const unsigned char* __restrict__ f1, int n1_, int* __restrict__ l1, int* __restrict__ c1) {
  const unsigned char* f; int n; int *l, *c;
  if (blockIdx.y == 0) { f = f0; n = n0_; l = l0; c = c0; }
  else                 { f = f1; n = n1_; l = l1; c = c1; }
  __shared__ int wsum[16];
  __shared__ int sbase;
  int i = blockIdx.x * 1024 + threadIdx.x;
  int wid = threadIdx.x >> 6, lane = threadIdx.x & 63;
  bool dem = (i < n) && f[i];
  unsigned long long mask = __ballot(dem);
  int before = __popcll(mask & ((1ull << lane) - 1ull));
  int wtot = __popcll(mask);
  if (lane == 0) wsum[wid] = wtot;
  __syncthreads();
  if (threadIdx.x == 0) {
    int t = 0;
#pragma unroll
    for (int w = 0; w < 16; ++w) { int v = wsum[w]; wsum[w] = t; t += v; }
    sbase = t ? atomicAdd(c, t) : 0;
  }
  __syncthreads();
  if (dem) l[sbase + wsum[wid] + before] = i;
}

// ---------------- L0 gather (paired, y=direction, GRID-STRIDE): f32 in, split mean out ----
// Output rows are NODE-indexed. 8-wide unrolled loads; adds strictly sequential (bit-identical).
__global__ void gather_f2s(const float* __restrict__ x0, const int* __restrict__ csr0,
                           const int* __restrict__ off0, const int* __restrict__ cnt0,
                           const int* __restrict__ list0, const int* __restrict__ n0Dev,
                           unsigned short* __restrict__ oh0, unsigned short* __restrict__ ol0,
                           const float* __restrict__ x1, const int* __restrict__ csr1,
                           const int* __restrict__ off1, const int* __restrict__ cnt1,
                           const int* __restrict__ list1, const int* __restrict__ n1Dev,
                           unsigned short* __restrict__ oh1, unsigned short* __restrict__ ol1) {
  const float* x; const int *csr, *offp, *cnt, *list, *nDev;
  unsigned short *oh, *ol;
  if (blockIdx.y == 0) { x = x0; csr = csr0; offp = off0; cnt = cnt0; list = list0; nDev = n0Dev; oh = oh0; ol = ol0; }
  else                 { x = x1; csr = csr1; offp = off1; cnt = cnt1; list = list1; nDev = n1Dev; oh = oh1; ol = ol1; }
  const int nRows = *nDev;
  const int c = threadIdx.x & 31;
  for (int r = blockIdx.x * 8 + (threadIdx.x >> 5); r < nRows; r += gridDim.x * 8) {
    int g = list[r];
    int o = offp[g], n = cnt[g];
    float4 acc = make_float4(0.f, 0.f, 0.f, 0.f);
    int j = 0;
    for (; j + 8 <= n; j += 8) {
      int s0 = csr[o + j],     s1 = csr[o + j + 1], s2 = csr[o + j + 2], s3 = csr[o + j + 3];
      int s4 = csr[o + j + 4], s5 = csr[o + j + 5], s6 = csr[o + j + 6], s7 = csr[o + j + 7];
      float4 v0 = reinterpret_cast<const float4*>(x + (size_t)s0 * HD)[c];
      float4 v1 = reinterpret_cast<const float4*>(x + (size_t)s1 * HD)[c];
      float4 v2 = reinterpret_cast<const float4*>(x + (size_t)s2 * HD)[c];
      float4 v3 = reinterpret_cast<const float4*>(x + (size_t)s3 * HD)[c];
      float4 v4 = reinterpret_cast<const float4*>(x + (size_t)s4 * HD)[c];
      float4 v5 = reinterpret_cast<const float4*>(x + (size_t)s5 * HD)[c];
      float4 v6 = reinterpret_cast<const float4*>(x + (size_t)s6 * HD)[c];
      float4 v7 = reinterpret_cast<const float4*>(x + (size_t)s7 * HD)[c];
      acc.x += v0.x; acc.y += v0.y; acc.z += v0.z; acc.w += v0.w;
      acc.x += v1.x; acc.y += v1.y; acc.z += v1.z; acc.w += v1.w;
      acc.x += v2.x; acc.y += v2.y; acc.z += v2.z; acc.w += v2.w;
      acc.x += v3.x; acc.y += v3.y; acc.z += v3.z; acc.w += v3.w;
      acc.x += v4.x; acc.y += v4.y; acc.z += v4.z; acc.w += v4.w;
      acc.x += v5.x; acc.y += v5.y; acc.z += v5.z; acc.w += v5.w;
      acc.x += v6.x; acc.y += v6.y; acc.z += v6.z; acc.w += v6.w;
      acc.x += v7.x; acc.y += v7.y; acc.z += v7.z; acc.w += v7.w;
    }
    for (; j + 4 <= n; j += 4) {
      int s0 = csr[o + j], s1 = csr[o + j + 1], s2 = csr[o + j + 2], s3 = csr[o + j + 3];
      float4 v0 = reinterpret_cast<const float4*>(x + (size_t)s0 * HD)[c];
      float4 v1 = reinterpret_cast<const float4*>(x + (size_t)s1 * HD)[c];
      float4 v2 = reinterpret_cast<const float4*>(x + (size_t)s2 * HD)[c];
      float4 v3 = reinterpret_cast<const float4*>(x + (size_t)s3 * HD)[c];
      acc.x += v0.x; acc.y += v0.y; acc.z += v0.z; acc.w += v0.w;
      acc.x += v1.x; acc.y += v1.y; acc.z += v1.z; acc.w += v1.w;
      acc.x += v2.x; acc.y += v2.y; acc.z += v2.z; acc.w += v2.w;
      acc.x += v3.x; acc.y += v3.y; acc.z += v3.z; acc.w += v3.w;
    }
    for (; j < n; ++j) {
      int s = csr[o + j];
      float4 v = reinterpret_cast<const float4*>(x + (size_t)s * HD)[c];
      acc.x += v.x; acc.y += v.y; acc.z += v.z; acc.w += v.w;
    }
    float inv = 1.0f / (float)max(n, 1);
    float4 m = make_float4(acc.x * inv, acc.y * inv, acc.z * inv, acc.w * inv);
    uint2 ph, pl;
    split4(m, ph, pl);
    reinterpret_cast<uint2*>(oh + (size_t)g * HD)[c] = ph;
    reinterpret_cast<uint2*>(ol + (size_t)g * HD)[c] = pl;
  }
}

// ---------------- merged weight prep: split_weights + fold(attn->MLP1) in one dispatch ------
__global__ void prep_weights(const float* __restrict__ Wl, const float* __restrict__ Wr,
                             const float* __restrict__ W2,
                             unsigned short* __restrict__ WLh, unsigned short* __restrict__ WLl,
                             unsigned short* __restrict__ WRh, unsigned short* __restrict__ WRl,
                             unsigned short* __restrict__ W2h, unsigned short* __restrict__ W2l,
                             const float* __restrict__ W1, const float* __restrict__ b1,
                             const float* __restrict__ attn_Win, const float* __restrict__ attn_bin,
                             const float* __restrict__ attn_Wout, const float* __restrict__ attn_bout,
                             unsigned short* __restrict__ Ah, unsigned short* __restrict__ Al,
                             unsigned short* __restrict__ Bh, unsigned short* __restrict__ Bl,
                             float* __restrict__ bc) {
  __shared__ float tA[2][128], tB[2][128];
  const int b = blockIdx.x;
  if (b < 512) {
    const int widx[6] = {0, 1, 3, 4, 5, 6};
    int i = b * 256 + threadIdx.x;
    if (i < 98304) {
      int m = i >> 14, e = i & 16383;
      int n = e >> 7, k = e & 127;
      size_t o = (size_t)m * 16384 + swzW(n, k, 128);
      splitf(Wl[(size_t)widx[m] * 16384 + e], WLh[o], WLl[o]);
      splitf(Wr[(size_t)widx[m] * 16384 + e], WRh[o], WRl[o]);
    } else if (i < 131072) {
      int j = i - 98304;
      int n = j >> 8, k = j & 255;
      size_t o = swzW(n, k, 256);
      splitf(W2[j], W2h[o], W2l[o]);
    }
    return;
  }
  // fold path: 128 blocks x (2 rows of 128 threads)
  const int sub = threadIdx.x >> 7, k = threadIdx.x & 127;
  const int r = (b - 512) * 2 + sub;
  const float* w1r = W1 + (size_t)r * 512;
  const float* Wout0 = attn_Wout;                 // module 0: drug_att <- dis_emb
  const float* Wout1 = attn_Wout + HD * HD;       // module 1: dis_att  <- drug_emb
  float ta = 0.0f, tb = 0.0f;
  for (int m = 0; m < HD; ++m) {
    ta += w1r[384 + m] * Wout1[m * HD + k];
    tb += w1r[256 + m] * Wout0[m * HD + k];
  }
  tA[sub][k] = ta; tB[sub][k] = tb;
  __syncthreads();
  const float* Wv0 = attn_Win + 2 * HD * HD;               // module 0 Wv
  const float* Wv1 = attn_Win + 3 * HD * HD + 2 * HD * HD; // module 1 Wv
  float accA = 0.0f, accB = 0.0f;
  for (int u = 0; u < HD; ++u) {
    accA += tA[sub][u] * Wv1[u * HD + k];
    accB += tB[sub][u] * Wv0[u * HD + k];
  }
  size_t o = swzW(r, k, 128);
  splitf(w1r[k] + accA, Ah[o], Al[o]);
  splitf(w1r[128 + k] + accB, Bh[o], Bl[o]);
  if (k == 0) {
    const float* bv0 = attn_bin + 2 * HD;
    const float* bv1 = attn_bin + 3 * HD + 2 * HD;
    float bb = b1[r];
    for (int m = 0; m < HD; ++m)
      bb += w1r[256 + m] * attn_bout[m] + w1r[384 + m] * attn_bout[HD + m];
    for (int u = 0; u < HD; ++u) bb += tB[sub][u] * bv0[u] + tA[sub][u] * bv1[u];
    bc[r] = bb;
  }
}

// ---------------- L0 dual GEMM (round-1 proven body): LDS-staged X1 + X2, 2-phase ----------
// C = relu( agg @ Wa + emb_self @ Wb + bias ), split-bf16 out.
struct L0Args {
  const unsigned short* X1h; const unsigned short* X1l;  // split agg (NODE-indexed)
  const float* x2f32;                                    // self emb table (f32)
  const int* rowNode;   // row -> node id (batch idx array, or demand list)
  const unsigned short* Wah; const unsigned short* Wal;  // swizzled Wl
  const unsigned short* Wbh; const unsigned short* Wbl;  // swizzled Wr
  const float* bias;
  const int* nRowsDev;                                   // nullptr -> NB
  unsigned short* Oh; unsigned short* Ol;
};

// single shared-LDS block for ALL l0_body instantiations (avoids per-instantiation LDS dup)
struct L0Shared {
  unsigned short sX1h[64][72];
  unsigned short sX1l[64][72];
  unsigned short sX2h[64][72];
  unsigned short sX2l[64][72];
  int sNode[64];
};

template <bool OBN>   // OBN: write outputs at node rows (list GEMMs) vs linear rows (batch)
__device__ inline void l0_body(const L0Args& A, int bx, int tid, L0Shared& S) {
  const int nRows = A.nRowsDev ? *A.nRowsDev : NB;
  const int row0 = bx * 64;
  if (row0 >= nRows) return;
  const int lane = tid & 63;
  const int wv = tid >> 6;
  const int quad = lane >> 4, m16 = lane & 15;
  const int n0 = wv * 32;

  // staging role: 4 threads per row, 16 elements each
  const int sr = tid >> 2;
  const int sk = (tid & 3) * 16;
  int gsrc = row0 + sr;
  if (gsrc > nRows - 1) gsrc = nRows - 1;
  const int node = A.rowNode[gsrc];
  if (OBN && (tid & 3) == 0) S.sNode[sr] = node;   // epilogue reads from LDS, not global

  f32x4 acc[4][2];
#pragma unroll
  for (int ct = 0; ct < 2; ++ct) {
    float b = A.bias[n0 + ct * 16 + m16];
    f32x4 bb = {b, b, b, b};
#pragma unroll
    for (int rt = 0; rt < 4; ++rt) acc[rt][ct] = bb;
  }

#pragma unroll 1
  for (int kc = 0; kc < HD; kc += 64) {
    // ---- stage X1 chunk (split bf16, node-indexed) ----
    {
      const unsigned short* p = A.X1h + (size_t)node * HD + kc + sk;
      *reinterpret_cast<short8*>(&S.sX1h[sr][sk])     = *reinterpret_cast<const short8*>(p);
      *reinterpret_cast<short8*>(&S.sX1h[sr][sk + 8]) = *reinterpret_cast<const short8*>(p + 8);
      const unsigned short* q = A.X1l + (size_t)node * HD + kc + sk;
      *reinterpret_cast<short8*>(&S.sX1l[sr][sk])     = *reinterpret_cast<const short8*>(q);
      *reinterpret_cast<short8*>(&S.sX1l[sr][sk + 8]) = *reinterpret_cast<const short8*>(q + 8);
    }
    // ---- stage X2 chunk (f32 emb -> in-register split), coalesced 4 thr/row ----
    {
      const float* p = A.x2f32 + (size_t)node * HD + kc + sk;
      short8 h0, l0, h1, l1;
      split8(p, h0, l0);
      split8(p + 8, h1, l1);
      *reinterpret_cast<short8*>(&S.sX2h[sr][sk])     = h0;
      *reinterpret_cast<short8*>(&S.sX2h[sr][sk + 8]) = h1;
      *reinterpret_cast<short8*>(&S.sX2l[sr][sk])     = l0;
      *reinterpret_cast<short8*>(&S.sX2l[sr][sk + 8]) = l1;
    }
    __syncthreads();

    // ---- compute: 2 MFMA k-steps per chunk ----
#pragma unroll
    for (int kk = 0; kk < 64; kk += 32) {
      const int ktile = (kc + kk) >> 5;
      short8 bah[2], bal[2], bbh[2], bbl[2];
#pragma unroll
      for (int ct = 0; ct < 2; ++ct) {
        size_t wo = ((size_t)(((n0 + ct * 16) >> 4) * 4 + ktile)) * 512 + (size_t)lane * 8;
        bah[ct] = *reinterpret_cast<const short8*>(A.Wah + wo);
        bal[ct] = *reinterpret_cast<const short8*>(A.Wal + wo);
        bbh[ct] = *reinterpret_cast<const short8*>(A.Wbh + wo);
        bbl[ct] = *reinterpret_cast<const short8*>(A.Wbl + wo);
      }
#pragma unroll
      for (int rt = 0; rt < 4; ++rt) {
        const int xr = rt * 16 + m16;
        const int xo = kk + quad * 8;
        short8 a1h = *reinterpret_cast<const short8*>(&S.sX1h[xr][xo]);
        short8 a1l = *reinterpret_cast<const short8*>(&S.sX1l[xr][xo]);
#pragma unroll
        for (int ct = 0; ct < 2; ++ct) {
          acc[rt][ct] = __builtin_amdgcn_mfma_f32_16x16x32_bf16(a1h, bah[ct], acc[rt][ct], 0, 0, 0);
          acc[rt][ct] = __builtin_amdgcn_mfma_f32_16x16x32_bf16(a1h, bal[ct], acc[rt][ct], 0, 0, 0);
          acc[rt][ct] = __builtin_amdgcn_mfma_f32_16x16x32_bf16(a1l, bah[ct], acc[rt][ct], 0, 0, 0);
        }
        short8 a2h = *reinterpret_cast<const short8*>(&S.sX2h[xr][xo]);
        short8 a2l = *reinterpret_cast<const short8*>(&S.sX2l[xr][xo]);
#pragma unroll
        for (int ct = 0; ct < 2; ++ct) {
          acc[rt][ct] = __builtin_amdgcn_mfma_f32_16x16x32_bf16(a2h, bbh[ct], acc[rt][ct], 0, 0, 0);
          acc[rt][ct] = __builtin_amdgcn_mfma_f32_16x16x32_bf16(a2h, bbl[ct], acc[rt][ct], 0, 0, 0);
          acc[rt][ct] = __builtin_amdgcn_mfma_f32_16x16x32_bf16(a2l, bbh[ct], acc[rt][ct], 0, 0, 0);
        }
      }
    }
    __syncthreads();
  }

  // epilogue: relu + split, D[m = quad*4+i][n = m16] per 16x16 tile
#pragma unroll
  for (int rt = 0; rt < 4; ++rt) {
#pragma unroll
    for (int i = 0; i < 4; ++i) {
      int m = row0 + rt * 16 + quad * 4 + i;
      if (m < nRows) {
        const int orow = OBN ? S.sNode[rt * 16 + quad * 4 + i] : m;
#pragma unroll
        for (int ct = 0; ct < 2; ++ct) {
          float v = fmaxf(acc[rt][ct][i], 0.0f);
          size_t o = (size_t)orow * HD + n0 + ct * 16 + m16;
          unsigned short h, l;
          splitf(v, h, l);
          A.Oh[o] = h; A.Ol[o] = l;
        }
      }
    }
  }
}

// all four L0 GEMMs (2 batch + 2 list), grid-stride over virtual blocks.
__global__ __launch_bounds__(256, 4) void l0_quad(L0Args a, L0Args b, L0Args c, L0Args d) {
  __shared__ L0Shared S;
  const int nA = NB / 64, nB2 = NB / 64;
  const int nc = (*c.nRowsDev + 63) >> 6;
  const int nd = (*d.nRowsDev + 63) >> 6;
  const int total = nA + nB2 + nc + nd;
  for (int vb = blockIdx.x; vb < total; vb += gridDim.x) {
    if (vb < nA)                 l0_body<false>(a, vb, threadIdx.x, S);
    else if (vb < nA + nB2)      l0_body<false>(b, vb - nA, threadIdx.x, S);
    else if (vb < nA + nB2 + nc) l0_body<true>(c, vb - nA - nB2, threadIdx.x, S);
    else                         l0_body<true>(d, vb - nA - nB2 - nc, threadIdx.x, S);
    __syncthreads();   // LDS reuse safety across virtual blocks
  }
}

// ---------------- fused batch tail: L1 gather + L1 dual pair -> MLP1 -> MLP2 -> dot ----
__global__ __launch_bounds__(256) void tail_fused(
    const unsigned short* __restrict__ tgDh, const unsigned short* __restrict__ tgDl,  // tg_dis (node rows)
    const unsigned short* __restrict__ tgRh, const unsigned short* __restrict__ tgRl,  // tg_drug
    const int* __restrict__ drug_idx, const int* __restrict__ dis_idx,
    const int* __restrict__ csrA, const int* __restrict__ offA, const int* __restrict__ cntA,  // di2dr
    const int* __restrict__ csrB, const int* __restrict__ offB, const int* __restrict__ cntB,  // d2di
    const unsigned short* __restrict__ dXh, const unsigned short* __restrict__ dXl,    // d1b (batch rows)
    const unsigned short* __restrict__ dYh, const unsigned short* __restrict__ dYl,    // s1b
    const unsigned short* __restrict__ WLah, const unsigned short* __restrict__ WLal,
    const unsigned short* __restrict__ WRah, const unsigned short* __restrict__ WRal,
    const unsigned short* __restrict__ WLbh, const unsigned short* __restrict__ WLbl,
    const unsigned short* __restrict__ WRbh, const unsigned short* __restrict__ WRbl,
    const float* __restrict__ biasA, const float* __restrict__ biasB,
    const unsigned short* __restrict__ Amh, const unsigned short* __restrict__ Aml,
    const unsigned short* __restrict__ Bmh, const unsigned short* __restrict__ Bml,
    const float* __restrict__ bc,
    const unsigned short* __restrict__ W2h, const unsigned short* __restrict__ W2l,
    const float* __restrict__ b2, const float* __restrict__ W3,
    const float* __restrict__ b3, float* __restrict__ out) {
  __shared__ unsigned short sA0h[32][136], sA0l[32][136];   // L1 agg (drug side)
  __shared__ unsigned short sA1h[32][136], sA1l[32][136];   // L1 agg (disease side)
  __shared__ unsigned short sX2h[32][72], sX2l[32][72];
  __shared__ unsigned short sP0h[32][136], sP0l[32][136], sP1h[32][136], sP1l[32][136];
  __shared__ float sRed[32][4];

  const int tid = threadIdx.x;
  const int lane = tid & 63, wv = tid >> 6;
  const int quad = lane >> 4, m16 = lane & 15;
  const int n0 = wv * 32;
  const int row0 = blockIdx.x * 32;
  const int sr = tid >> 3, sk = (tid & 7) * 8;     // 8 thr/row, one short8 each
  const size_t grow = (size_t)(row0 + sr) * HD;

  // ---- phase 0: L1 mean aggregation into LDS (exact gather_s2s numerics) ----
  {
    const int c = tid & 31;
    for (int rr = tid >> 5; rr < 32; rr += 8) {
      const int row = row0 + rr;
#pragma unroll
      for (int side = 0; side < 2; ++side) {
        const int node = side ? dis_idx[row] : drug_idx[row];
        const int* csr = side ? csrB : csrA;
        const int o = side ? offB[node] : offA[node];
        const int n = side ? cntB[node] : cntA[node];
        const unsigned short* xh = side ? tgRh : tgDh;
        const unsigned short* xl = side ? tgRl : tgDl;
        float4 acc = make_float4(0.f, 0.f, 0.f, 0.f);
        auto accum = [&](uint2 hh, uint2 ll) {
          acc.x += __uint_as_float(hh.x << 16) + __uint_as_float(ll.x << 16);
          acc.y += __uint_as_float(hh.x & 0xffff0000u) + __uint_as_float(ll.x & 0xffff0000u);
          acc.z += __uint_as_float(hh.y << 16) + __uint_as_float(ll.y << 16);
          acc.w += __uint_as_float(hh.y & 0xffff0000u) + __uint_as_float(ll.y & 0xffff0000u);
        };
        int j = 0;
        for (; j + 4 <= n; j += 4) {
          int p0 = csr[o + j], p1 = csr[o + j + 1], p2 = csr[o + j + 2], p3 = csr[o + j + 3];
          uint2 h0 = reinterpret_cast<const uint2*>(xh + (size_t)p0 * HD)[c];
          uint2 l0 = reinterpret_cast<const uint2*>(xl + (size_t)p0 * HD)[c];
          uint2 h1 = reinterpret_cast<const uint2*>(xh + (size_t)p1 * HD)[c];
          uint2 l1 = reinterpret_cast<const uint2*>(xl + (size_t)p1 * HD)[c];
          uint2 h2 = reinterpret_cast<const uint2*>(xh + (size_t)p2 * HD)[c];
          uint2 l2 = reinterpret_cast<const uint2*>(xl + (size_t)p2 * HD)[c];
          uint2 h3 = reinterpret_cast<const uint2*>(xh + (size_t)p3 * HD)[c];
          uint2 l3 = reinterpret_cast<const uint2*>(xl + (size_t)p3 * HD)[c];
          accum(h0, l0); accum(h1, l1); accum(h2, l2); accum(h3, l3);
        }
        for (; j < n; ++j) {
          int p = csr[o + j];
          uint2 hh = reinterpret_cast<const uint2*>(xh + (size_t)p * HD)[c];
          uint2 ll = reinterpret_cast<const uint2*>(xl + (size_t)p * HD)[c];
          accum(hh, ll);
        }
        float inv = 1.0f / (float)max(n, 1);
        float4 m = make_float4(acc.x * inv, acc.y * inv, acc.z * inv, acc.w * inv);
        uint2 ph, pl;
        split4(m, ph, pl);
        if (side) {
          *reinterpret_cast<uint2*>(&sA1h[rr][c * 4]) = ph;
          *reinterpret_cast<uint2*>(&sA1l[rr][c * 4]) = pl;
        } else {
          *reinterpret_cast<uint2*>(&sA0h[rr][c * 4]) = ph;
          *reinterpret_cast<uint2*>(&sA0l[rr][c * 4]) = pl;
        }
      }
    }
  }

  // ---- stage 1: two dual 32x128 L1 GEMMs -> de (sP0), se (sP1), relu+split ----
  for (int half = 0; half < 2; ++half) {
    const unsigned short (*A1h)[136] = half ? sA1h : sA0h;
    const unsigned short (*A1l)[136] = half ? sA1l : sA0l;
    const unsigned short* X2h = half ? dYh : dXh;
    const unsigned short* X2l = half ? dYl : dXl;
    const unsigned short* Wah = half ? WLbh : WLah;
    const unsigned short* Wal = half ? WLbl : WLal;
    const unsigned short* Wbh = half ? WRbh : WRah;
    const unsigned short* Wbl = half ? WRbl : WRal;
    const float* bias = half ? biasB : biasA;

    f32x4 acc[2][2];
#pragma unroll
    for (int ct = 0; ct < 2; ++ct) {
      float b = bias[n0 + ct * 16 + m16];
      f32x4 bb = {b, b, b, b};
      acc[0][ct] = bb; acc[1][ct] = bb;
    }

    for (int kc = 0; kc < HD; kc += 64) {
      __syncthreads();   // guards phase-0 completion (first iter) / prior sX2 reads
      *reinterpret_cast<short8*>(&sX2h[sr][sk]) = *reinterpret_cast<const short8*>(X2h + grow + kc + sk);
      *reinterpret_cast<short8*>(&sX2l[sr][sk]) = *reinterpret_cast<const short8*>(X2l + grow + kc + sk);
      __syncthreads();
#pragma unroll
      for (int kk = 0; kk < 64; kk += 32) {
        const int ktile = (kc + kk) >> 5;
        short8 bah[2], bal[2], bbh[2], bbl[2];
#pragma unroll
        for (int ct = 0; ct < 2; ++ct) {
          size_t wo = ((size_t)(((n0 + ct * 16) >> 4) * 4 + ktile)) * 512 + (size_t)lane * 8;
          bah[ct] = *reinterpret_cast<const short8*>(Wah + wo);
          bal[ct] = *reinterpret_cast<const short8*>(Wal + wo);
          bbh[ct] = *reinterpret_cast<const short8*>(Wbh + wo);
          bbl[ct] = *reinterpret_cast<const short8*>(Wbl + wo);
        }
#pragma unroll
        for (int rt = 0; rt < 2; ++rt) {
          const int xr = rt * 16 + m16;
          const int x1o = kc + kk + quad * 8;
          const int x2o = kk + quad * 8;
          short8 a1h = *reinterpret_cast<const short8*>(&A1h[xr][x1o]);
          short8 a1l = *reinterpret_cast<const short8*>(&A1l[xr][x1o]);
#pragma unroll
          for (int ct = 0; ct < 2; ++ct) {
            acc[rt][ct] = __builtin_amdgcn_mfma_f32_16x16x32_bf16(a1h, bah[ct], acc[rt][ct], 0, 0, 0);
            acc[rt][ct] = __builtin_amdgcn_mfma_f32_16x16x32_bf16(a1h, bal[ct], acc[rt][ct], 0, 0, 0);
            acc[rt][ct] = __builtin_amdgcn_mfma_f32_16x16x32_bf16(a1l, bah[ct], acc[rt][ct], 0, 0, 0);
          }
          short8 a2h = *reinterpret_cast<const short8*>(&sX2h[xr][x2o]);
          short8 a2l = *reinterpret_cast<const short8*>(&sX2l[xr][x2o]);
#pragma unroll
          for (int ct = 0; ct < 2; ++ct) {
            acc[rt][ct] = __builtin_amdgcn_mfma_f32_16x16x32_bf16(a2h, bbh[ct], acc[rt][ct], 0, 0, 0);
            acc[rt][ct] = __builtin_amdgcn_mfma_f32_16x16x32_bf16(a2h, bbl[ct], acc[rt][ct], 0, 0, 0);
            acc[rt][ct] = __builtin_amdgcn_mfma_f32_16x16x32_bf16(a2l, bbh[ct], acc[rt][ct], 0, 0, 0);
          }
        }
      }
    }
    // epilogue -> LDS (relu + split); sP not read until after next sync
    unsigned short (*dh)[136] = half ? sP1h : sP0h;
    unsigned short (*dl)[136] = half ? sP1l : sP0l;
#pragma unroll
    for (int rt = 0; rt < 2; ++rt)
#pragma unroll
      for (int ct = 0; ct < 2; ++ct)
#pragma unroll
        for (int i = 0; i < 4; ++i) {
          float v = fmaxf(acc[rt][ct][i], 0.0f);
          unsigned short h, l;
          splitf(v, h, l);
          dh[rt * 16 + quad * 4 + i][n0 + ct * 16 + m16] = h;
          dl[rt * 16 + quad * 4 + i][n0 + ct * 16 + m16] = l;
        }
  }
  __syncthreads();

  // ---- MLP1: h1[32x256] = relu(de@Am + se@Bm + bc) ----
  f32x4 acc1[2][4];
#pragma unroll
  for (int ct = 0; ct < 4; ++ct) {
    const int nc_ = (ct < 2) ? (n0 + ct * 16) : (128 + n0 + (ct - 2) * 16);
    float b = bc[nc_ + m16];
    f32x4 bb = {b, b, b, b};
    acc1[0][ct] = bb; acc1[1][ct] = bb;
  }
#pragma unroll
  for (int kt = 0; kt < 4; ++kt) {
    const int xo = kt * 32 + quad * 8;
    short8 adh[2], adl[2], ash[2], asl[2];
#pragma unroll
    for (int rt = 0; rt < 2; ++rt) {
      const int xr = rt * 16 + m16;
      adh[rt] = *reinterpret_cast<const short8*>(&sP0h[xr][xo]);
      adl[rt] = *reinterpret_cast<const short8*>(&sP0l[xr][xo]);
      ash[rt] = *reinterpret_cast<const short8*>(&sP1h[xr][xo]);
      asl[rt] = *reinterpret_cast<const short8*>(&sP1l[xr][xo]);
    }
#pragma unroll
    for (int ct = 0; ct < 4; ++ct) {
      const int nc_ = (ct < 2) ? (n0 + ct * 16) : (128 + n0 + (ct - 2) * 16);
      size_t wo = ((size_t)((nc_ >> 4) * 4 + kt)) * 512 + (size_t)lane * 8;
      short8 wah = *reinterpret_cast<const short8*>(Amh + wo);
      short8 wal = *reinterpret_cast<const short8*>(Aml + wo);
      short8 wbh = *reinterpret_cast<const short8*>(Bmh + wo);
      short8 wbl = *reinterpret_cast<const short8*>(Bml + wo);
#pragma unroll
      for (int rt = 0; rt < 2; ++rt) {
        acc1[rt][ct] = __builtin_amdgcn_mfma_f32_16x16x32_bf16(adh[rt], wah, acc1[rt][ct], 0, 0, 0);
        acc1[rt][ct] = __builtin_amdgcn_mfma_f32_16x16x32_bf16(adh[rt], wal, acc1[rt][ct], 0, 0, 0);
        acc1[rt][ct] = __builtin_amdgcn_mfma_f32_16x16x32_bf16(adl[rt], wah, acc1[rt][ct], 0, 0, 0);
        acc1[rt][ct] = __builtin_amdgcn_mfma_f32_16x16x32_bf16(ash[rt], wbh, acc1[rt][ct], 0, 0, 0);
        acc1[rt][ct] = __builtin_amdgcn_mfma_f32_16x16x32_bf16(ash[rt], wbl, acc1[rt][ct], 0, 0, 0);
        acc1[rt][ct] = __builtin_amdgcn_mfma_f32_16x16x32_bf16(asl[rt], wbh, acc1[rt][ct], 0, 0, 0);
      }
    }
  }
  __syncthreads();   // all de/se reads done; reuse sP for h1
#pragma unroll
  for (int ct = 0; ct < 4; ++ct)
#pragma unroll
    for (int rt = 0; rt < 2; ++rt)
#pragma unroll
      for (int i = 0; i < 4; ++i) {
        float v = fmaxf(acc1[rt][ct][i], 0.0f);
        unsigned short h, l;
        splitf(v, h, l);
        const int rr = rt * 16 + quad * 4 + i;
        if (ct < 2) {
          const int cc = n0 + ct * 16 + m16;
          sP0h[rr][cc] = h; sP0l[rr][cc] = l;
        } else {
          const int cc = n0 + (ct - 2) * 16 + m16;
          sP1h[rr][cc] = h; sP1l[rr][cc] = l;
        }
      }
  __syncthreads();

  // ---- MLP2: h2[32x128] = relu(h1@W2 + b2), K=256 from sP0 (k<128) and sP1 (k>=128) ----
  f32x4 acc2[2][2];
#pragma unroll
  for (int ct = 0; ct < 2; ++ct) {
    float b = b2[n0 + ct * 16 + m16];
    f32x4 bb = {b, b, b, b};
    acc2[0][ct] = bb; acc2[1][ct] = bb;
  }
#pragma unroll
  for (int kt = 0; kt < 8; ++kt) {
    const unsigned short (*ph)[136] = (kt < 4) ? sP0h : sP1h;
    const unsigned short (*pl)[136] = (kt < 4) ? sP0l : sP1l;
    const int xo = (kt & 3) * 32 + quad * 8;
    short8 ah[2], al[2];
#pragma unroll
    for (int rt = 0; rt < 2; ++rt) {
      const int xr = rt * 16 + m16;
      ah[rt] = *reinterpret_cast<const short8*>(&ph[xr][xo]);
      al[rt] = *reinterpret_cast<const short8*>(&pl[xr][xo]);
    }
#pragma unroll
    for (int ct = 0; ct < 2; ++ct) {
      size_t wo = ((size_t)(((n0 + ct * 16) >> 4) * 8 + kt)) * 512 + (size_t)lane * 8;
      short8 wh = *reinterpret_cast<const short8*>(W2h + wo);
      short8 wl = *reinterpret_cast<const short8*>(W2l + wo);
#pragma unroll
      for (int rt = 0; rt < 2; ++rt) {
        acc2[rt][ct] = __builtin_amdgcn_mfma_f32_16x16x32_bf16(ah[rt], wh, acc2[rt][ct], 0, 0, 0);
        acc2[rt][ct] = __builtin_amdgcn_mfma_f32_16x16x32_bf16(ah[rt], wl, acc2[rt][ct], 0, 0, 0);
        acc2[rt][ct] = __builtin_amdgcn_mfma_f32_16x16x32_bf16(al[rt], wh, acc2[rt][ct], 0, 0, 0);
      }
    }
  }

  // ---- final dot with W3 (relu on h2 in-register) ----
  const float w3a = W3[n0 + m16];
  const float w3b = W3[n0 + 16 + m16];
#pragma unroll
  for (int rt = 0; rt < 2; ++rt)
#pragma unroll
    for (int i = 0; i < 4; ++i) {
      float p = fmaxf(acc2[rt][0][i], 0.0f) * w3a + fmaxf(acc2[rt][1][i], 0.0f) * w3b;
      p += __shfl_xor(p, 1);
      p += __shfl_xor(p, 2);
      p += __shfl_xor(p, 4);
      p += __shfl_xor(p, 8);
      if (m16 == 0) sRed[rt * 16 + quad * 4 + i][wv] = p;
    }
  __syncthreads();
  if (tid < 32)
    out[row0 + tid] = sRed[tid][0] + sRed[tid][1] + sRed[tid][2] + sRed[tid][3] + b3[0];
}

}  // namespace

extern "C" void kernel_launch(void* const* d_in, const int* in_sizes, int n_in,
                              void* d_out, int out_size, void* d_ws, size_t ws_size,
                              hipStream_t stream) {
  const int* src_d2di  = (const int*)d_in[0];
  const int* dst_d2di  = (const int*)d_in[1];
  const int* src_di2dr = (const int*)d_in[2];
  const int* dst_di2dr = (const int*)d_in[3];
  const int* drug_idx  = (const int*)d_in[4];
  const int* dis_idx   = (const int*)d_in[5];
  const float* emb_drug = (const float*)d_in[6];
  const float* emb_dis  = (const float*)d_in[7];
  const float* Wl = (const float*)d_in[8];
  const float* bl = (const float*)d_in[9];
  const float* Wr = (const float*)d_in[10];
  const float* attn_Win  = (const float*)d_in[11];
  const float* attn_bin  = (const float*)d_in[12];
  const float* attn_Wout = (const float*)d_in[13];
  const float* attn_bout = (const float*)d_in[14];
  const float* W1 = (const float*)d_in[15];
  const float* b1 = (const float*)d_in[16];
  const float* W2 = (const float*)d_in[17];
  const float* b2 = (const float*)d_in[18];
  const float* W3 = (const float*)d_in[19];
  const float* b3 = (const float*)d_in[20];
  float* out = (float*)d_out;

  // ---- workspace carve (16B-aligned float units) ----
  float* ws = (float*)d_ws;
  size_t off = 0;
  auto carve = [&](size_t nfloats) {
    float* p = ws + off;
    off += (nfloats + 3) & ~(size_t)3;
    return p;
  };
  auto carveU = [&](size_t nush) { return (unsigned short*)carve((nush + 1) / 2); };

  // zeroed region (one memset): cnt/cursor ints + uchar flags + nctr
  int* cnt_dis     = (int*)carve(NDI);
  int* cnt_drug    = (int*)carve(NDR);
  int* cursor_dis  = (int*)carve(NDI);
  int* cursor_drug = (int*)carve(NDR);
  unsigned char* fb_dis  = (unsigned char*)carve((NDI + 3) / 4);
  unsigned char* fb_drug = (unsigned char*)carve((NDR + 3) / 4);
  unsigned char* fd_dis  = (unsigned char*)carve((NDI + 3) / 4);
  unsigned char* fd_drug = (unsigned char*)carve((NDR + 3) / 4);
  int* nctr        = (int*)carve(8);  // [0]=n_list_dis, [1]=n_list_drug
  const size_t zero_bytes = off * sizeof(float);
  // not zeroed
  int* off_dis   = (int*)carve(NDI);
  int* off_drug  = (int*)carve(NDR);
  int* list_dis  = (int*)carve(NDI);
  int* list_drug = (int*)carve(NDR);
  int* csr_d2di  = (int*)carve(NE);
  int* csr_di2dr = (int*)carve(NE);
  int* bsum_dis  = (int*)carve(256);
  int* bsum_drug = (int*)carve(256);

  // big split-bf16 buffers (NODE-indexed)
  unsigned short* aggh_dis  = carveU((size_t)NDI * HD);  // L0 mean agg
  unsigned short* aggl_dis  = carveU((size_t)NDI * HD);
  unsigned short* aggh_drug = carveU((size_t)NDR * HD);
  unsigned short* aggl_drug = carveU((size_t)NDR * HD);
  unsigned short* tgh_dis   = carveU((size_t)NDI * HD);  // L0 transformed (dis1_s0)
  unsigned short* tgl_dis   = carveU((size_t)NDI * HD);
  unsigned short* tgh_drug  = carveU((size_t)NDR * HD);  // L0 transformed (drug1_s1)
  unsigned short* tgl_drug  = carveU((size_t)NDR * HD);
  // batch-sized split buffers
  unsigned short* d1bh = carveU((size_t)NB * HD);  // drug1 (stack0) at batch rows
  unsigned short* d1bl = carveU((size_t)NB * HD);
  unsigned short* s1bh = carveU((size_t)NB * HD);  // dis1 (stack1) at batch rows
  unsigned short* s1bl = carveU((size_t)NB * HD);
  // weights (split, B-fragment swizzled)
  unsigned short* WLh = carveU(6 * 16384);
  unsigned short* WLl = carveU(6 * 16384);
  unsigned short* WRh = carveU(6 * 16384);
  unsigned short* WRl = carveU(6 * 16384);
  unsigned short* W2h = carveU(32768);
  unsigned short* W2l = carveU(32768);
  unsigned short* Amh = carveU(32768);
  unsigned short* Aml = carveU(32768);
  unsigned short* Bmh = carveU(32768);
  unsigned short* Bml = carveU(32768);
  // f32 small
  float* bc = carve(2 * HD);

  dim3 blk(256);
  const size_t WS = 16384;  // one 128x128 weight slot (elements)
  const int EB = (NE + 255) / 256;

  hipMemsetAsync(cnt_dis, 0, zero_bytes, stream);

  // weight prep (merged split + fold; independent of graph work)
  prep_weights<<<640, blk, 0, stream>>>(Wl, Wr, W2, WLh, WLl, WRh, WRl, W2h, W2l,
                                        W1, b1, attn_Win, attn_bin, attn_Wout, attn_bout,
                                        Amh, Aml, Bmh, Bml, bc);

  // demand marking (edge-parallel)
  batch_mark<<<(2 * NB + 255) / 256, blk, 0, stream>>>(drug_idx, dis_idx, fb_drug, fb_dis, fd_drug, fd_dis);
  edge_mark<<<dim3(EB, 2), blk, 0, stream>>>(src_d2di, dst_d2di, src_di2dr, dst_di2dr,
                                             fb_dis, fb_drug, fd_drug, fd_dis);

  // filtered degree counts; demand lists (1 atomic per 1024-thread block)
  count_f<<<dim3(EB, 2), blk, 0, stream>>>(dst_d2di, dst_di2dr, fd_dis, fd_drug, cnt_dis, cnt_drug);
  compact_list<<<dim3((NDR + 1023) / 1024, 2), dim3(1024), 0, stream>>>(
      fd_dis, NDI, list_dis, nctr + 0, fd_drug, NDR, list_drug, nctr + 1);

  // CSR offsets via deterministic 3-phase scan (filtered counts)
  scan1y<<<dim3((NDR + 1023) / 1024, 2), blk, 0, stream>>>(cnt_dis, NDI, off_dis, bsum_dis,
                                                           cnt_drug, NDR, off_drug, bsum_drug);
  scan2<<<2, blk, 0, stream>>>(bsum_dis, (NDI + 1023) / 1024, bsum_drug, (NDR + 1023) / 1024);
  scan3y<<<dim3((NDR + 255) / 256, 2), blk, 0, stream>>>(off_dis, NDI, bsum_dis, off_drug, NDR, bsum_drug);

  // filtered CSR scatter
  csr_f<<<dim3(EB, 2), blk, 0, stream>>>(src_d2di, dst_d2di, src_di2dr, dst_di2dr, NE,
                                         fd_dis, fd_drug,
                                         off_dis, cursor_dis, csr_d2di,
                                         off_drug, cursor_drug, csr_di2dr);

  // layer-0 mean aggregation at NODE rows (grid-stride, both directions)
  gather_f2s<<<dim3(1024, 2), blk, 0, stream>>>(
      emb_drug, csr_d2di, off_dis, cnt_dis, list_dis, nctr + 0, aggh_dis, aggl_dis,
      emb_dis, csr_di2dr, off_drug, cnt_drug, list_drug, nctr + 1, aggh_drug, aggl_drug);

  // all four L0 GEMMs in one grid-stride dispatch:
  //   a: dis1b (stack1, slot3) at batch rows; b: drug1b (stack0, slot1) at batch rows
  //   c: dis1_s0 (slot0) over list -> tg_dis (node rows)
  //   d: drug1_s1 (slot4) over list -> tg_drug (node rows)
  {
    L0Args z{};
    auto mk = [&](const unsigned short* X1h_, const unsigned short* X1l_, const float* x2_,
                  const int* rowNode_,
                  const unsigned short* Wah_, const unsigned short* Wal_,
                  const unsigned short* Wbh_, const unsigned short* Wbl_,
                  const float* bias_, const int* nDev,
                  unsigned short* Oh_, unsigned short* Ol_) {
      L0Args g = z;
      g.X1h = X1h_; g.X1l = X1l_; g.x2f32 = x2_;
      g.rowNode = rowNode_;
      g.Wah = Wah_; g.Wal = Wal_; g.Wbh = Wbh_; g.Wbl = Wbl_;
      g.bias = bias_; g.nRowsDev = nDev; g.Oh = Oh_; g.Ol = Ol_;
      return g;
    };
    L0Args a = mk(aggh_dis, aggl_dis, emb_dis, dis_idx,
                  WLh + 3 * WS, WLl + 3 * WS, WRh + 3 * WS, WRl + 3 * WS, bl + 4 * HD,
                  nullptr, s1bh, s1bl);
    L0Args b = mk(aggh_drug, aggl_drug, emb_drug, drug_idx,
                  WLh + 1 * WS, WLl + 1 * WS, WRh + 1 * WS, WRl + 1 * WS, bl + 1 * HD,
                  nullptr, d1bh, d1bl);
    L0Args c = mk(aggh_dis, aggl_dis, emb_dis, list_dis,
                  WLh + 0 * WS, WLl + 0 * WS, WRh + 0 * WS, WRl + 0 * WS, bl + 0 * HD,
                  nctr + 0, tgh_dis, tgl_dis);
    L0Args d = mk(aggh_drug, aggl_drug, emb_drug, list_drug,
                  WLh + 4 * WS, WLl + 4 * WS, WRh + 4 * WS, WRl + 4 * WS, bl + 5 * HD,
                  nctr + 1, tgh_drug, tgl_drug);
    l0_quad<<<2048, blk, 0, stream>>>(a, b, c, d);
  }

  // fused batch tail: L1 gather (LDS) + L1 pair (slots 2/5) -> MLP1 -> MLP2 -> dot(W3)
  tail_fused<<<NB / 32, blk, 0, stream>>>(
      tgh_dis, tgl_dis, tgh_drug, tgl_drug,
      drug_idx, dis_idx,
      csr_di2dr, off_drug, cnt_drug,
      csr_d2di, off_dis, cnt_dis,
      d1bh, d1bl, s1bh, s1bl,
      WLh + 2 * WS, WLl + 2 * WS, WRh + 2 * WS, WRl + 2 * WS,
      WLh + 5 * WS, WLl + 5 * WS, WRh + 5 * WS, WRl + 5 * WS,
      bl + 3 * HD, bl + 6 * HD,
      Amh, Aml, Bmh, Bml, bc, W2h, W2l, b2, W3, b3, out);

  (void)in_sizes; (void)n_in; (void)out_size; (void)ws_size;
}

// Round 8
// 439.777 us; speedup vs baseline: 1.0455x; 1.0387x over previous
//
#include <hip/hip_runtime.h>

namespace {

constexpr int HD  = 128;      // hidden dim
constexpr int NE  = 600000;   // edges per direction
constexpr int NDR = 200000;   // drugs
constexpr int NDI = 100000;   // diseases
constexpr int NB  = 8192;     // link batch

typedef __attribute__((ext_vector_type(8))) short short8;   // 8 bf16 in 4 VGPRs
typedef __attribute__((ext_vector_type(4))) float f32x4;

// ---- split-bf16 helpers: x = hi + lo (truncated), ~16 mantissa bits total ----
__device__ inline void splitf(float x, unsigned short& h, unsigned short& l) {
  unsigned u = __float_as_uint(x);
  h = (unsigned short)(u >> 16);
  float r = x - __uint_as_float(u & 0xffff0000u);   // exact residual
  l = (unsigned short)(__float_as_uint(r) >> 16);
}
__device__ inline void split4(const float4& v, uint2& ph, uint2& pl) {
  unsigned ux = __float_as_uint(v.x), uy = __float_as_uint(v.y);
  unsigned uz = __float_as_uint(v.z), uw = __float_as_uint(v.w);
  ph.x = (ux >> 16) | (uy & 0xffff0000u);
  ph.y = (uz >> 16) | (uw & 0xffff0000u);
  float rx = v.x - __uint_as_float(ux & 0xffff0000u);
  float ry = v.y - __uint_as_float(uy & 0xffff0000u);
  float rz = v.z - __uint_as_float(uz & 0xffff0000u);
  float rw = v.w - __uint_as_float(uw & 0xffff0000u);
  pl.x = (__float_as_uint(rx) >> 16) | (__float_as_uint(ry) & 0xffff0000u);
  pl.y = (__float_as_uint(rz) >> 16) | (__float_as_uint(rw) & 0xffff0000u);
}
// load 8 contiguous f32 and split into hi/lo bf16 fragments in-register
__device__ inline void split8(const float* p, short8& h8, short8& l8) {
  float4 v0 = *reinterpret_cast<const float4*>(p);
  float4 v1 = *reinterpret_cast<const float4*>(p + 4);
  uint2 h0, l0, h1, l1;
  split4(v0, h0, l0);
  split4(v1, h1, l1);
  union { unsigned u[4]; short8 s; } uh, ul;
  uh.u[0] = h0.x; uh.u[1] = h0.y; uh.u[2] = h1.x; uh.u[3] = h1.y;
  ul.u[0] = l0.x; ul.u[1] = l0.y; ul.u[2] = l1.x; ul.u[3] = l1.y;
  h8 = uh.s; l8 = ul.s;
}

// ---- MFMA B-fragment swizzled W layout ----
// Tile = 16 n-rows x 32 k. Element (n,k) -> tile*512 + quad(k)*128 + (n&15)*8 + (k&7),
// so a wave's B-fragment load is base + lane*8 (fully coalesced 1KB).
__device__ inline size_t swzW(int n, int k, int K) {
  return ((size_t)((n >> 4) * (K >> 5) + (k >> 5))) * 512 +
         (size_t)(((k >> 3) & 3) * 128 + (n & 15) * 8 + (k & 7));
}

// ---------------- batch flag + demand flag for batch nodes ----------------
__global__ void batch_mark(const int* __restrict__ drug_idx, const int* __restrict__ dis_idx,
                           unsigned char* __restrict__ fb_drug, unsigned char* __restrict__ fb_dis,
                           unsigned char* __restrict__ fd_drug, unsigned char* __restrict__ fd_dis) {
  int i = blockIdx.x * 256 + threadIdx.x;
  if (i < NB) { int g = drug_idx[i]; fb_drug[g] = 1; fd_drug[g] = 1; }
  else if (i < 2 * NB) { int g = dis_idx[i - NB]; fb_dis[g] = 1; fd_dis[g] = 1; }
}

// ---------------- edge-parallel demand mark: src of edges into batch dst ----------------
__global__ void edge_mark(const int* __restrict__ s0, const int* __restrict__ d0,   // d2di
                          const int* __restrict__ s1, const int* __restrict__ d1,   // di2dr
                          const unsigned char* __restrict__ fb_dis,
                          const unsigned char* __restrict__ fb_drug,
                          unsigned char* __restrict__ fd_drug, unsigned char* __restrict__ fd_dis) {
  int e = blockIdx.x * 256 + threadIdx.x;
  if (e >= NE) return;
  if (blockIdx.y == 0) { if (fb_dis[d0[e]]) fd_drug[s0[e]] = 1; }
  else                 { if (fb_drug[d1[e]]) fd_dis[s1[e]] = 1; }
}

// ---------------- filtered degree counts (demanded dst only) ----------------
__global__ void count_f(const int* __restrict__ d0, const int* __restrict__ d1,
                        const unsigned char* __restrict__ fd_dis,
                        const unsigned char* __restrict__ fd_drug,
                        int* __restrict__ c0, int* __restrict__ c1) {
  int e = blockIdx.x * 256 + threadIdx.x;
  if (e >= NE) return;
  if (blockIdx.y == 0) { int d = d0[e]; if (fd_dis[d]) atomicAdd(&c0[d], 1); }
  else                 { int d = d1[e]; if (fd_drug[d]) atomicAdd(&c1[d], 1); }
}

// ---------------- 3-phase exclusive scan, y selects dis/drug ----------------
__global__ void scan1y(const int* __restrict__ in0, int n0_, int* __restrict__ out0, int* __restrict__ bs0,
                       const int* __restrict__ in1, int n1_, int* __restrict__ out1, int* __restrict__ bs1) {
  const int* in; int n; int* outp; int* bs;
  if (blockIdx.y == 0) { in = in0; n = n0_; outp = out0; bs = bs0; }
  else                 { in = in1; n = n1_; outp = out1; bs = bs1; }
  if (blockIdx.x * 1024 >= n) return;
  __shared__ int s[256];
  int t = threadIdx.x;
  int idx = blockIdx.x * 1024 + t * 4;
  int4 v = make_int4(0, 0, 0, 0);
  if (idx + 3 < n) v = *reinterpret_cast<const int4*>(in + idx);
  else {
    if (idx     < n) v.x = in[idx];
    if (idx + 1 < n) v.y = in[idx + 1];
    if (idx + 2 < n) v.z = in[idx + 2];
    if (idx + 3 < n) v.w = in[idx + 3];
  }
  int tsum = v.x + v.y + v.z + v.w;
  s[t] = tsum;
  __syncthreads();
  for (int o = 1; o < 256; o <<= 1) {
    int x = (t >= o) ? s[t - o] : 0;
    __syncthreads();
    s[t] += x;
    __syncthreads();
  }
  int excl = s[t] - tsum;
  if (idx     < n) outp[idx]     = excl;
  if (idx + 1 < n) outp[idx + 1] = excl + v.x;
  if (idx + 2 < n) outp[idx + 2] = excl + v.x + v.y;
  if (idx + 3 < n) outp[idx + 3] = excl + v.x + v.y + v.z;
  if (t == 255) bs[blockIdx.x] = s[255];
}

__global__ void scan2(int* __restrict__ bs0, int nb0, int* __restrict__ bs1, int nb1) {
  int* bsum = (blockIdx.x == 0) ? bs0 : bs1;
  int nb = (blockIdx.x == 0) ? nb0 : nb1;
  __shared__ int s[256];
  int t = threadIdx.x;
  int v = (t < nb) ? bsum[t] : 0;
  s[t] = v;
  __syncthreads();
  for (int o = 1; o < 256; o <<= 1) {
    int x = (t >= o) ? s[t - o] : 0;
    __syncthreads();
    s[t] += x;
    __syncthreads();
  }
  if (t < nb) bsum[t] = s[t] - v;
}

__global__ void scan3y(int* __restrict__ out0, int n0_, const int* __restrict__ bs0,
                       int* __restrict__ out1, int n1_, const int* __restrict__ bs1) {
  int* outp; int n; const int* bs;
  if (blockIdx.y == 0) { outp = out0; n = n0_; bs = bs0; }
  else                 { outp = out1; n = n1_; bs = bs1; }
  int i = blockIdx.x * 256 + threadIdx.x;
  if (i < n) outp[i] += bs[i >> 10];
}

// ---------------- filtered CSR bucket scatter ----------------
__global__ void csr_f(const int* __restrict__ s0, const int* __restrict__ d0,
                      const int* __restrict__ s1, const int* __restrict__ d1, int nE,
                      const unsigned char* __restrict__ fd_dis,
                      const unsigned char* __restrict__ fd_drug,
                      const int* __restrict__ off0, int* __restrict__ cur0, int* __restrict__ csr0,
                      const int* __restrict__ off1, int* __restrict__ cur1, int* __restrict__ csr1) {
  int e = blockIdx.x * 256 + threadIdx.x;
  if (e >= nE) return;
  if (blockIdx.y == 0) {
    int d = d0[e];
    if (fd_dis[d]) csr0[off0[d] + atomicAdd(&cur0[d], 1)] = s0[e];
  } else {
    int d = d1[e];
    if (fd_drug[d]) csr1[off1[d] + atomicAdd(&cur1[d], 1)] = s1[e];
  }
}

// ---------------- demand flags -> list, ONE atomic per 1024-thread block ----------------
__global__ __launch_bounds__(1024) void compact_list(
    const unsigned char* __restrict__ f0, int n0_, int* __restrict__ l0, int* __restrict__ c0,
    const unsigned char* __restrict__ f1, int n1_, int* __restrict__ l1, int* __restrict__ c1) {
  const unsigned char* f; int n; int *l, *c;
  if (blockIdx.y == 0) { f = f0; n = n0_; l = l0; c = c0; }
  else                 { f = f1; n = n1_; l = l1; c = c1; }
  __shared__ int wsum[16];
  __shared__ int sbase;
  int i = blockIdx.x * 1024 + threadIdx.x;
  int wid = threadIdx.x >> 6, lane = threadIdx.x & 63;
  bool dem = (i < n) && f[i];
  unsigned long long mask = __ballot(dem);
  int before = __popcll(mask & ((1ull << lane) - 1ull));
  int wtot = __popcll(mask);
  if (lane == 0) wsum[wid] = wtot;
  __syncthreads();
  if (threadIdx.x == 0) {
    int t = 0;
#pragma unroll
    for (int w = 0; w < 16; ++w) { int v = wsum[w]; wsum[w] = t; t += v; }
    sbase = t ? atomicAdd(c, t) : 0;
  }
  __syncthreads();
  if (dem) l[sbase + wsum[wid] + before] = i;
}

// ---------------- L0 gather (paired, y=direction, GRID-STRIDE): f32 in, split mean out ----
// Output rows are NODE-indexed. 8-wide unrolled loads; adds strictly sequential (bit-identical).
__global__ void gather_f2s(const float* __restrict__ x0, const int* __restrict__ csr0,
                           const int* __restrict__ off0, const int* __restrict__ cnt0,
                           const int* __restrict__ list0, const int* __restrict__ n0Dev,
                           unsigned short* __restrict__ oh0, unsigned short* __restrict__ ol0,
                           const float* __restrict__ x1, const int* __restrict__ csr1,
                           const int* __restrict__ off1, const int* __restrict__ cnt1,
                           const int* __restrict__ list1, const int* __restrict__ n1Dev,
                           unsigned short* __restrict__ oh1, unsigned short* __restrict__ ol1) {
  const float* x; const int *csr, *offp, *cnt, *list, *nDev;
  unsigned short *oh, *ol;
  if (blockIdx.y == 0) { x = x0; csr = csr0; offp = off0; cnt = cnt0; list = list0; nDev = n0Dev; oh = oh0; ol = ol0; }
  else                 { x = x1; csr = csr1; offp = off1; cnt = cnt1; list = list1; nDev = n1Dev; oh = oh1; ol = ol1; }
  const int nRows = *nDev;
  const int c = threadIdx.x & 31;
  for (int r = blockIdx.x * 8 + (threadIdx.x >> 5); r < nRows; r += gridDim.x * 8) {
    int g = list[r];
    int o = offp[g], n = cnt[g];
    float4 acc = make_float4(0.f, 0.f, 0.f, 0.f);
    int j = 0;
    for (; j + 8 <= n; j += 8) {
      int s0 = csr[o + j],     s1 = csr[o + j + 1], s2 = csr[o + j + 2], s3 = csr[o + j + 3];
      int s4 = csr[o + j + 4], s5 = csr[o + j + 5], s6 = csr[o + j + 6], s7 = csr[o + j + 7];
      float4 v0 = reinterpret_cast<const float4*>(x + (size_t)s0 * HD)[c];
      float4 v1 = reinterpret_cast<const float4*>(x + (size_t)s1 * HD)[c];
      float4 v2 = reinterpret_cast<const float4*>(x + (size_t)s2 * HD)[c];
      float4 v3 = reinterpret_cast<const float4*>(x + (size_t)s3 * HD)[c];
      float4 v4 = reinterpret_cast<const float4*>(x + (size_t)s4 * HD)[c];
      float4 v5 = reinterpret_cast<const float4*>(x + (size_t)s5 * HD)[c];
      float4 v6 = reinterpret_cast<const float4*>(x + (size_t)s6 * HD)[c];
      float4 v7 = reinterpret_cast<const float4*>(x + (size_t)s7 * HD)[c];
      acc.x += v0.x; acc.y += v0.y; acc.z += v0.z; acc.w += v0.w;
      acc.x += v1.x; acc.y += v1.y; acc.z += v1.z; acc.w += v1.w;
      acc.x += v2.x; acc.y += v2.y; acc.z += v2.z; acc.w += v2.w;
      acc.x += v3.x; acc.y += v3.y; acc.z += v3.z; acc.w += v3.w;
      acc.x += v4.x; acc.y += v4.y; acc.z += v4.z; acc.w += v4.w;
      acc.x += v5.x; acc.y += v5.y; acc.z += v5.z; acc.w += v5.w;
      acc.x += v6.x; acc.y += v6.y; acc.z += v6.z; acc.w += v6.w;
      acc.x += v7.x; acc.y += v7.y; acc.z += v7.z; acc.w += v7.w;
    }
    for (; j + 4 <= n; j += 4) {
      int s0 = csr[o + j], s1 = csr[o + j + 1], s2 = csr[o + j + 2], s3 = csr[o + j + 3];
      float4 v0 = reinterpret_cast<const float4*>(x + (size_t)s0 * HD)[c];
      float4 v1 = reinterpret_cast<const float4*>(x + (size_t)s1 * HD)[c];
      float4 v2 = reinterpret_cast<const float4*>(x + (size_t)s2 * HD)[c];
      float4 v3 = reinterpret_cast<const float4*>(x + (size_t)s3 * HD)[c];
      acc.x += v0.x; acc.y += v0.y; acc.z += v0.z; acc.w += v0.w;
      acc.x += v1.x; acc.y += v1.y; acc.z += v1.z; acc.w += v1.w;
      acc.x += v2.x; acc.y += v2.y; acc.z += v2.z; acc.w += v2.w;
      acc.x += v3.x; acc.y += v3.y; acc.z += v3.z; acc.w += v3.w;
    }
    for (; j < n; ++j) {
      int s = csr[o + j];
      float4 v = reinterpret_cast<const float4*>(x + (size_t)s * HD)[c];
      acc.x += v.x; acc.y += v.y; acc.z += v.z; acc.w += v.w;
    }
    float inv = 1.0f / (float)max(n, 1);
    float4 m = make_float4(acc.x * inv, acc.y * inv, acc.z * inv, acc.w * inv);
    uint2 ph, pl;
    split4(m, ph, pl);
    reinterpret_cast<uint2*>(oh + (size_t)g * HD)[c] = ph;
    reinterpret_cast<uint2*>(ol + (size_t)g * HD)[c] = pl;
  }
}

// ---------------- merged weight prep: split_weights + fold(attn->MLP1) in one dispatch ------
__global__ void prep_weights(const float* __restrict__ Wl, const float* __restrict__ Wr,
                             const float* __restrict__ W2,
                             unsigned short* __restrict__ WLh, unsigned short* __restrict__ WLl,
                             unsigned short* __restrict__ WRh, unsigned short* __restrict__ WRl,
                             unsigned short* __restrict__ W2h, unsigned short* __restrict__ W2l,
                             const float* __restrict__ W1, const float* __restrict__ b1,
                             const float* __restrict__ attn_Win, const float* __restrict__ attn_bin,
                             const float* __restrict__ attn_Wout, const float* __restrict__ attn_bout,
                             unsigned short* __restrict__ Ah, unsigned short* __restrict__ Al,
                             unsigned short* __restrict__ Bh, unsigned short* __restrict__ Bl,
                             float* __restrict__ bc) {
  __shared__ float tA[2][128], tB[2][128];
  const int b = blockIdx.x;
  if (b < 512) {
    const int widx[6] = {0, 1, 3, 4, 5, 6};
    int i = b * 256 + threadIdx.x;
    if (i < 98304) {
      int m = i >> 14, e = i & 16383;
      int n = e >> 7, k = e & 127;
      size_t o = (size_t)m * 16384 + swzW(n, k, 128);
      splitf(Wl[(size_t)widx[m] * 16384 + e], WLh[o], WLl[o]);
      splitf(Wr[(size_t)widx[m] * 16384 + e], WRh[o], WRl[o]);
    } else if (i < 131072) {
      int j = i - 98304;
      int n = j >> 8, k = j & 255;
      size_t o = swzW(n, k, 256);
      splitf(W2[j], W2h[o], W2l[o]);
    }
    return;
  }
  // fold path: 128 blocks x (2 rows of 128 threads)
  const int sub = threadIdx.x >> 7, k = threadIdx.x & 127;
  const int r = (b - 512) * 2 + sub;
  const float* w1r = W1 + (size_t)r * 512;
  const float* Wout0 = attn_Wout;                 // module 0: drug_att <- dis_emb
  const float* Wout1 = attn_Wout + HD * HD;       // module 1: dis_att  <- drug_emb
  float ta = 0.0f, tb = 0.0f;
  for (int m = 0; m < HD; ++m) {
    ta += w1r[384 + m] * Wout1[m * HD + k];
    tb += w1r[256 + m] * Wout0[m * HD + k];
  }
  tA[sub][k] = ta; tB[sub][k] = tb;
  __syncthreads();
  const float* Wv0 = attn_Win + 2 * HD * HD;               // module 0 Wv
  const float* Wv1 = attn_Win + 3 * HD * HD + 2 * HD * HD; // module 1 Wv
  float accA = 0.0f, accB = 0.0f;
  for (int u = 0; u < HD; ++u) {
    accA += tA[sub][u] * Wv1[u * HD + k];
    accB += tB[sub][u] * Wv0[u * HD + k];
  }
  size_t o = swzW(r, k, 128);
  splitf(w1r[k] + accA, Ah[o], Al[o]);
  splitf(w1r[128 + k] + accB, Bh[o], Bl[o]);
  if (k == 0) {
    const float* bv0 = attn_bin + 2 * HD;
    const float* bv1 = attn_bin + 3 * HD + 2 * HD;
    float bb = b1[r];
    for (int m = 0; m < HD; ++m)
      bb += w1r[256 + m] * attn_bout[m] + w1r[384 + m] * attn_bout[HD + m];
    for (int u = 0; u < HD; ++u) bb += tB[sub][u] * bv0[u] + tA[sub][u] * bv1[u];
    bc[r] = bb;
  }
}

// ---------------- L0 dual GEMM (round-1 proven body): LDS-staged X1 + X2, 2-phase ----------
// C = relu( agg @ Wa + emb_self @ Wb + bias ), split-bf16 out.
struct L0Args {
  const unsigned short* X1h; const unsigned short* X1l;  // split agg (NODE-indexed)
  const float* x2f32;                                    // self emb table (f32)
  const int* rowNode;   // row -> node id (batch idx array, or demand list)
  const unsigned short* Wah; const unsigned short* Wal;  // swizzled Wl
  const unsigned short* Wbh; const unsigned short* Wbl;  // swizzled Wr
  const float* bias;
  const int* nRowsDev;                                   // nullptr -> NB
  unsigned short* Oh; unsigned short* Ol;
};

// single shared-LDS block for ALL l0_body instantiations (avoids per-instantiation LDS dup)
struct L0Shared {
  unsigned short sX1h[64][72];
  unsigned short sX1l[64][72];
  unsigned short sX2h[64][72];
  unsigned short sX2l[64][72];
  int sNode[64];
};

template <bool OBN>   // OBN: write outputs at node rows (list GEMMs) vs linear rows (batch)
__device__ inline void l0_body(const L0Args& A, int bx, int tid, L0Shared& S) {
  const int nRows = A.nRowsDev ? *A.nRowsDev : NB;
  const int row0 = bx * 64;
  if (row0 >= nRows) return;
  const int lane = tid & 63;
  const int wv = tid >> 6;
  const int quad = lane >> 4, m16 = lane & 15;
  const int n0 = wv * 32;

  // staging role: 4 threads per row, 16 elements each
  const int sr = tid >> 2;
  const int sk = (tid & 3) * 16;
  int gsrc = row0 + sr;
  if (gsrc > nRows - 1) gsrc = nRows - 1;
  const int node = A.rowNode[gsrc];
  if (OBN && (tid & 3) == 0) S.sNode[sr] = node;   // epilogue reads from LDS, not global

  f32x4 acc[4][2];
#pragma unroll
  for (int ct = 0; ct < 2; ++ct) {
    float b = A.bias[n0 + ct * 16 + m16];
    f32x4 bb = {b, b, b, b};
#pragma unroll
    for (int rt = 0; rt < 4; ++rt) acc[rt][ct] = bb;
  }

#pragma unroll 1
  for (int kc = 0; kc < HD; kc += 64) {
    // ---- stage X1 chunk (split bf16, node-indexed) ----
    {
      const unsigned short* p = A.X1h + (size_t)node * HD + kc + sk;
      *reinterpret_cast<short8*>(&S.sX1h[sr][sk])     = *reinterpret_cast<const short8*>(p);
      *reinterpret_cast<short8*>(&S.sX1h[sr][sk + 8]) = *reinterpret_cast<const short8*>(p + 8);
      const unsigned short* q = A.X1l + (size_t)node * HD + kc + sk;
      *reinterpret_cast<short8*>(&S.sX1l[sr][sk])     = *reinterpret_cast<const short8*>(q);
      *reinterpret_cast<short8*>(&S.sX1l[sr][sk + 8]) = *reinterpret_cast<const short8*>(q + 8);
    }
    // ---- stage X2 chunk (f32 emb -> in-register split), coalesced 4 thr/row ----
    {
      const float* p = A.x2f32 + (size_t)node * HD + kc + sk;
      short8 h0, l0, h1, l1;
      split8(p, h0, l0);
      split8(p + 8, h1, l1);
      *reinterpret_cast<short8*>(&S.sX2h[sr][sk])     = h0;
      *reinterpret_cast<short8*>(&S.sX2h[sr][sk + 8]) = h1;
      *reinterpret_cast<short8*>(&S.sX2l[sr][sk])     = l0;
      *reinterpret_cast<short8*>(&S.sX2l[sr][sk + 8]) = l1;
    }
    __syncthreads();

    // ---- compute: 2 MFMA k-steps per chunk ----
#pragma unroll
    for (int kk = 0; kk < 64; kk += 32) {
      const int ktile = (kc + kk) >> 5;
      short8 bah[2], bal[2], bbh[2], bbl[2];
#pragma unroll
      for (int ct = 0; ct < 2; ++ct) {
        size_t wo = ((size_t)(((n0 + ct * 16) >> 4) * 4 + ktile)) * 512 + (size_t)lane * 8;
        bah[ct] = *reinterpret_cast<const short8*>(A.Wah + wo);
        bal[ct] = *reinterpret_cast<const short8*>(A.Wal + wo);
        bbh[ct] = *reinterpret_cast<const short8*>(A.Wbh + wo);
        bbl[ct] = *reinterpret_cast<const short8*>(A.Wbl + wo);
      }
#pragma unroll
      for (int rt = 0; rt < 4; ++rt) {
        const int xr = rt * 16 + m16;
        const int xo = kk + quad * 8;
        short8 a1h = *reinterpret_cast<const short8*>(&S.sX1h[xr][xo]);
        short8 a1l = *reinterpret_cast<const short8*>(&S.sX1l[xr][xo]);
#pragma unroll
        for (int ct = 0; ct < 2; ++ct) {
          acc[rt][ct] = __builtin_amdgcn_mfma_f32_16x16x32_bf16(a1h, bah[ct], acc[rt][ct], 0, 0, 0);
          acc[rt][ct] = __builtin_amdgcn_mfma_f32_16x16x32_bf16(a1h, bal[ct], acc[rt][ct], 0, 0, 0);
          acc[rt][ct] = __builtin_amdgcn_mfma_f32_16x16x32_bf16(a1l, bah[ct], acc[rt][ct], 0, 0, 0);
        }
        short8 a2h = *reinterpret_cast<const short8*>(&S.sX2h[xr][xo]);
        short8 a2l = *reinterpret_cast<const short8*>(&S.sX2l[xr][xo]);
#pragma unroll
        for (int ct = 0; ct < 2; ++ct) {
          acc[rt][ct] = __builtin_amdgcn_mfma_f32_16x16x32_bf16(a2h, bbh[ct], acc[rt][ct], 0, 0, 0);
          acc[rt][ct] = __builtin_amdgcn_mfma_f32_16x16x32_bf16(a2h, bbl[ct], acc[rt][ct], 0, 0, 0);
          acc[rt][ct] = __builtin_amdgcn_mfma_f32_16x16x32_bf16(a2l, bbh[ct], acc[rt][ct], 0, 0, 0);
        }
      }
    }
    __syncthreads();
  }

  // epilogue: relu + split, D[m = quad*4+i][n = m16] per 16x16 tile
#pragma unroll
  for (int rt = 0; rt < 4; ++rt) {
#pragma unroll
    for (int i = 0; i < 4; ++i) {
      int m = row0 + rt * 16 + quad * 4 + i;
      if (m < nRows) {
        const int orow = OBN ? S.sNode[rt * 16 + quad * 4 + i] : m;
#pragma unroll
        for (int ct = 0; ct < 2; ++ct) {
          float v = fmaxf(acc[rt][ct][i], 0.0f);
          size_t o = (size_t)orow * HD + n0 + ct * 16 + m16;
          unsigned short h, l;
          splitf(v, h, l);
          A.Oh[o] = h; A.Ol[o] = l;
        }
      }
    }
  }
}

// all four L0 GEMMs (2 batch + 2 list), grid-stride over virtual blocks.
// plain launch bounds: let the allocator settle at ~124 VGPR (round-1 point, no spill);
// LDS 37.4KB still admits 4 blocks/CU.
__global__ __launch_bounds__(256) void l0_quad(L0Args a, L0Args b, L0Args c, L0Args d) {
  __shared__ L0Shared S;
  const int nA = NB / 64, nB2 = NB / 64;
  const int nc = (*c.nRowsDev + 63) >> 6;
  const int nd = (*d.nRowsDev + 63) >> 6;
  const int total = nA + nB2 + nc + nd;
  for (int vb = blockIdx.x; vb < total; vb += gridDim.x) {
    if (vb < nA)                 l0_body<false>(a, vb, threadIdx.x, S);
    else if (vb < nA + nB2)      l0_body<false>(b, vb - nA, threadIdx.x, S);
    else if (vb < nA + nB2 + nc) l0_body<true>(c, vb - nA - nB2, threadIdx.x, S);
    else                         l0_body<true>(d, vb - nA - nB2 - nc, threadIdx.x, S);
    __syncthreads();   // LDS reuse safety across virtual blocks
  }
}

// ---------------- fused batch tail: L1 gather + L1 dual pair -> MLP1 -> MLP2 -> dot ----
__global__ __launch_bounds__(256) void tail_fused(
    const unsigned short* __restrict__ tgDh, const unsigned short* __restrict__ tgDl,  // tg_dis (node rows)
    const unsigned short* __restrict__ tgRh, const unsigned short* __restrict__ tgRl,  // tg_drug
    const int* __restrict__ drug_idx, const int* __restrict__ dis_idx,
    const int* __restrict__ csrA, const int* __restrict__ offA, const int* __restrict__ cntA,  // di2dr
    const int* __restrict__ csrB, const int* __restrict__ offB, const int* __restrict__ cntB,  // d2di
    const unsigned short* __restrict__ dXh, const unsigned short* __restrict__ dXl,    // d1b (batch rows)
    const unsigned short* __restrict__ dYh, const unsigned short* __restrict__ dYl,    // s1b
    const unsigned short* __restrict__ WLah, const unsigned short* __restrict__ WLal,
    const unsigned short* __restrict__ WRah, const unsigned short* __restrict__ WRal,
    const unsigned short* __restrict__ WLbh, const unsigned short* __restrict__ WLbl,
    const unsigned short* __restrict__ WRbh, const unsigned short* __restrict__ WRbl,
    const float* __restrict__ biasA, const float* __restrict__ biasB,
    const unsigned short* __restrict__ Amh, const unsigned short* __restrict__ Aml,
    const unsigned short* __restrict__ Bmh, const unsigned short* __restrict__ Bml,
    const float* __restrict__ bc,
    const unsigned short* __restrict__ W2h, const unsigned short* __restrict__ W2l,
    const float* __restrict__ b2, const float* __restrict__ W3,
    const float* __restrict__ b3, float* __restrict__ out) {
  __shared__ unsigned short sA0h[32][136], sA0l[32][136];   // L1 agg (drug side)
  __shared__ unsigned short sA1h[32][136], sA1l[32][136];   // L1 agg (disease side)
  __shared__ unsigned short sX2h[32][72], sX2l[32][72];
  __shared__ unsigned short sP0h[32][136], sP0l[32][136], sP1h[32][136], sP1l[32][136];
  __shared__ float sRed[32][4];

  const int tid = threadIdx.x;
  const int lane = tid & 63, wv = tid >> 6;
  const int quad = lane >> 4, m16 = lane & 15;
  const int n0 = wv * 32;
  const int row0 = blockIdx.x * 32;
  const int sr = tid >> 3, sk = (tid & 7) * 8;     // 8 thr/row, one short8 each
  const size_t grow = (size_t)(row0 + sr) * HD;

  // ---- phase 0: L1 mean aggregation into LDS (exact gather_s2s numerics) ----
  {
    const int c = tid & 31;
    for (int rr = tid >> 5; rr < 32; rr += 8) {
      const int row = row0 + rr;
#pragma unroll
      for (int side = 0; side < 2; ++side) {
        const int node = side ? dis_idx[row] : drug_idx[row];
        const int* csr = side ? csrB : csrA;
        const int o = side ? offB[node] : offA[node];
        const int n = side ? cntB[node] : cntA[node];
        const unsigned short* xh = side ? tgRh : tgDh;
        const unsigned short* xl = side ? tgRl : tgDl;
        float4 acc = make_float4(0.f, 0.f, 0.f, 0.f);
        auto accum = [&](uint2 hh, uint2 ll) {
          acc.x += __uint_as_float(hh.x << 16) + __uint_as_float(ll.x << 16);
          acc.y += __uint_as_float(hh.x & 0xffff0000u) + __uint_as_float(ll.x & 0xffff0000u);
          acc.z += __uint_as_float(hh.y << 16) + __uint_as_float(ll.y << 16);
          acc.w += __uint_as_float(hh.y & 0xffff0000u) + __uint_as_float(ll.y & 0xffff0000u);
        };
        int j = 0;
        for (; j + 4 <= n; j += 4) {
          int p0 = csr[o + j], p1 = csr[o + j + 1], p2 = csr[o + j + 2], p3 = csr[o + j + 3];
          uint2 h0 = reinterpret_cast<const uint2*>(xh + (size_t)p0 * HD)[c];
          uint2 l0 = reinterpret_cast<const uint2*>(xl + (size_t)p0 * HD)[c];
          uint2 h1 = reinterpret_cast<const uint2*>(xh + (size_t)p1 * HD)[c];
          uint2 l1 = reinterpret_cast<const uint2*>(xl + (size_t)p1 * HD)[c];
          uint2 h2 = reinterpret_cast<const uint2*>(xh + (size_t)p2 * HD)[c];
          uint2 l2 = reinterpret_cast<const uint2*>(xl + (size_t)p2 * HD)[c];
          uint2 h3 = reinterpret_cast<const uint2*>(xh + (size_t)p3 * HD)[c];
          uint2 l3 = reinterpret_cast<const uint2*>(xl + (size_t)p3 * HD)[c];
          accum(h0, l0); accum(h1, l1); accum(h2, l2); accum(h3, l3);
        }
        for (; j < n; ++j) {
          int p = csr[o + j];
          uint2 hh = reinterpret_cast<const uint2*>(xh + (size_t)p * HD)[c];
          uint2 ll = reinterpret_cast<const uint2*>(xl + (size_t)p * HD)[c];
          accum(hh, ll);
        }
        float inv = 1.0f / (float)max(n, 1);
        float4 m = make_float4(acc.x * inv, acc.y * inv, acc.z * inv, acc.w * inv);
        uint2 ph, pl;
        split4(m, ph, pl);
        if (side) {
          *reinterpret_cast<uint2*>(&sA1h[rr][c * 4]) = ph;
          *reinterpret_cast<uint2*>(&sA1l[rr][c * 4]) = pl;
        } else {
          *reinterpret_cast<uint2*>(&sA0h[rr][c * 4]) = ph;
          *reinterpret_cast<uint2*>(&sA0l[rr][c * 4]) = pl;
        }
      }
    }
  }

  // ---- stage 1: two dual 32x128 L1 GEMMs -> de (sP0), se (sP1), relu+split ----
  for (int half = 0; half < 2; ++half) {
    const unsigned short (*A1h)[136] = half ? sA1h : sA0h;
    const unsigned short (*A1l)[136] = half ? sA1l : sA0l;
    const unsigned short* X2h = half ? dYh : dXh;
    const unsigned short* X2l = half ? dYl : dXl;
    const unsigned short* Wah = half ? WLbh : WLah;
    const unsigned short* Wal = half ? WLbl : WLal;
    const unsigned short* Wbh = half ? WRbh : WRah;
    const unsigned short* Wbl = half ? WRbl : WRal;
    const float* bias = half ? biasB : biasA;

    f32x4 acc[2][2];
#pragma unroll
    for (int ct = 0; ct < 2; ++ct) {
      float b = bias[n0 + ct * 16 + m16];
      f32x4 bb = {b, b, b, b};
      acc[0][ct] = bb; acc[1][ct] = bb;
    }

    for (int kc = 0; kc < HD; kc += 64) {
      __syncthreads();   // guards phase-0 completion (first iter) / prior sX2 reads
      *reinterpret_cast<short8*>(&sX2h[sr][sk]) = *reinterpret_cast<const short8*>(X2h + grow + kc + sk);
      *reinterpret_cast<short8*>(&sX2l[sr][sk]) = *reinterpret_cast<const short8*>(X2l + grow + kc + sk);
      __syncthreads();
#pragma unroll
      for (int kk = 0; kk < 64; kk += 32) {
        const int ktile = (kc + kk) >> 5;
        short8 bah[2], bal[2], bbh[2], bbl[2];
#pragma unroll
        for (int ct = 0; ct < 2; ++ct) {
          size_t wo = ((size_t)(((n0 + ct * 16) >> 4) * 4 + ktile)) * 512 + (size_t)lane * 8;
          bah[ct] = *reinterpret_cast<const short8*>(Wah + wo);
          bal[ct] = *reinterpret_cast<const short8*>(Wal + wo);
          bbh[ct] = *reinterpret_cast<const short8*>(Wbh + wo);
          bbl[ct] = *reinterpret_cast<const short8*>(Wbl + wo);
        }
#pragma unroll
        for (int rt = 0; rt < 2; ++rt) {
          const int xr = rt * 16 + m16;
          const int x1o = kc + kk + quad * 8;
          const int x2o = kk + quad * 8;
          short8 a1h = *reinterpret_cast<const short8*>(&A1h[xr][x1o]);
          short8 a1l = *reinterpret_cast<const short8*>(&A1l[xr][x1o]);
#pragma unroll
          for (int ct = 0; ct < 2; ++ct) {
            acc[rt][ct] = __builtin_amdgcn_mfma_f32_16x16x32_bf16(a1h, bah[ct], acc[rt][ct], 0, 0, 0);
            acc[rt][ct] = __builtin_amdgcn_mfma_f32_16x16x32_bf16(a1h, bal[ct], acc[rt][ct], 0, 0, 0);
            acc[rt][ct] = __builtin_amdgcn_mfma_f32_16x16x32_bf16(a1l, bah[ct], acc[rt][ct], 0, 0, 0);
          }
          short8 a2h = *reinterpret_cast<const short8*>(&sX2h[xr][x2o]);
          short8 a2l = *reinterpret_cast<const short8*>(&sX2l[xr][x2o]);
#pragma unroll
          for (int ct = 0; ct < 2; ++ct) {
            acc[rt][ct] = __builtin_amdgcn_mfma_f32_16x16x32_bf16(a2h, bbh[ct], acc[rt][ct], 0, 0, 0);
            acc[rt][ct] = __builtin_amdgcn_mfma_f32_16x16x32_bf16(a2h, bbl[ct], acc[rt][ct], 0, 0, 0);
            acc[rt][ct] = __builtin_amdgcn_mfma_f32_16x16x32_bf16(a2l, bbh[ct], acc[rt][ct], 0, 0, 0);
          }
        }
      }
    }
    // epilogue -> LDS (relu + split); sP not read until after next sync
    unsigned short (*dh)[136] = half ? sP1h : sP0h;
    unsigned short (*dl)[136] = half ? sP1l : sP0l;
#pragma unroll
    for (int rt = 0; rt < 2; ++rt)
#pragma unroll
      for (int ct = 0; ct < 2; ++ct)
#pragma unroll
        for (int i = 0; i < 4; ++i) {
          float v = fmaxf(acc[rt][ct][i], 0.0f);
          unsigned short h, l;
          splitf(v, h, l);
          dh[rt * 16 + quad * 4 + i][n0 + ct * 16 + m16] = h;
          dl[rt * 16 + quad * 4 + i][n0 + ct * 16 + m16] = l;
        }
  }
  __syncthreads();

  // ---- MLP1: h1[32x256] = relu(de@Am + se@Bm + bc) ----
  f32x4 acc1[2][4];
#pragma unroll
  for (int ct = 0; ct < 4; ++ct) {
    const int nc_ = (ct < 2) ? (n0 + ct * 16) : (128 + n0 + (ct - 2) * 16);
    float b = bc[nc_ + m16];
    f32x4 bb = {b, b, b, b};
    acc1[0][ct] = bb; acc1[1][ct] = bb;
  }
#pragma unroll
  for (int kt = 0; kt < 4; ++kt) {
    const int xo = kt * 32 + quad * 8;
    short8 adh[2], adl[2], ash[2], asl[2];
#pragma unroll
    for (int rt = 0; rt < 2; ++rt) {
      const int xr = rt * 16 + m16;
      adh[rt] = *reinterpret_cast<const short8*>(&sP0h[xr][xo]);
      adl[rt] = *reinterpret_cast<const short8*>(&sP0l[xr][xo]);
      ash[rt] = *reinterpret_cast<const short8*>(&sP1h[xr][xo]);
      asl[rt] = *reinterpret_cast<const short8*>(&sP1l[xr][xo]);
    }
#pragma unroll
    for (int ct = 0; ct < 4; ++ct) {
      const int nc_ = (ct < 2) ? (n0 + ct * 16) : (128 + n0 + (ct - 2) * 16);
      size_t wo = ((size_t)((nc_ >> 4) * 4 + kt)) * 512 + (size_t)lane * 8;
      short8 wah = *reinterpret_cast<const short8*>(Amh + wo);
      short8 wal = *reinterpret_cast<const short8*>(Aml + wo);
      short8 wbh = *reinterpret_cast<const short8*>(Bmh + wo);
      short8 wbl = *reinterpret_cast<const short8*>(Bml + wo);
#pragma unroll
      for (int rt = 0; rt < 2; ++rt) {
        acc1[rt][ct] = __builtin_amdgcn_mfma_f32_16x16x32_bf16(adh[rt], wah, acc1[rt][ct], 0, 0, 0);
        acc1[rt][ct] = __builtin_amdgcn_mfma_f32_16x16x32_bf16(adh[rt], wal, acc1[rt][ct], 0, 0, 0);
        acc1[rt][ct] = __builtin_amdgcn_mfma_f32_16x16x32_bf16(adl[rt], wah, acc1[rt][ct], 0, 0, 0);
        acc1[rt][ct] = __builtin_amdgcn_mfma_f32_16x16x32_bf16(ash[rt], wbh, acc1[rt][ct], 0, 0, 0);
        acc1[rt][ct] = __builtin_amdgcn_mfma_f32_16x16x32_bf16(ash[rt], wbl, acc1[rt][ct], 0, 0, 0);
        acc1[rt][ct] = __builtin_amdgcn_mfma_f32_16x16x32_bf16(asl[rt], wbh, acc1[rt][ct], 0, 0, 0);
      }
    }
  }
  __syncthreads();   // all de/se reads done; reuse sP for h1
#pragma unroll
  for (int ct = 0; ct < 4; ++ct)
#pragma unroll
    for (int rt = 0; rt < 2; ++rt)
#pragma unroll
      for (int i = 0; i < 4; ++i) {
        float v = fmaxf(acc1[rt][ct][i], 0.0f);
        unsigned short h, l;
        splitf(v, h, l);
        const int rr = rt * 16 + quad * 4 + i;
        if (ct < 2) {
          const int cc = n0 + ct * 16 + m16;
          sP0h[rr][cc] = h; sP0l[rr][cc] = l;
        } else {
          const int cc = n0 + (ct - 2) * 16 + m16;
          sP1h[rr][cc] = h; sP1l[rr][cc] = l;
        }
      }
  __syncthreads();

  // ---- MLP2: h2[32x128] = relu(h1@W2 + b2), K=256 from sP0 (k<128) and sP1 (k>=128) ----
  f32x4 acc2[2][2];
#pragma unroll
  for (int ct = 0; ct < 2; ++ct) {
    float b = b2[n0 + ct * 16 + m16];
    f32x4 bb = {b, b, b, b};
    acc2[0][ct] = bb; acc2[1][ct] = bb;
  }
#pragma unroll
  for (int kt = 0; kt < 8; ++kt) {
    const unsigned short (*ph)[136] = (kt < 4) ? sP0h : sP1h;
    const unsigned short (*pl)[136] = (kt < 4) ? sP0l : sP1l;
    const int xo = (kt & 3) * 32 + quad * 8;
    short8 ah[2], al[2];
#pragma unroll
    for (int rt = 0; rt < 2; ++rt) {
      const int xr = rt * 16 + m16;
      ah[rt] = *reinterpret_cast<const short8*>(&ph[xr][xo]);
      al[rt] = *reinterpret_cast<const short8*>(&pl[xr][xo]);
    }
#pragma unroll
    for (int ct = 0; ct < 2; ++ct) {
      size_t wo = ((size_t)(((n0 + ct * 16) >> 4) * 8 + kt)) * 512 + (size_t)lane * 8;
      short8 wh = *reinterpret_cast<const short8*>(W2h + wo);
      short8 wl = *reinterpret_cast<const short8*>(W2l + wo);
#pragma unroll
      for (int rt = 0; rt < 2; ++rt) {
        acc2[rt][ct] = __builtin_amdgcn_mfma_f32_16x16x32_bf16(ah[rt], wh, acc2[rt][ct], 0, 0, 0);
        acc2[rt][ct] = __builtin_amdgcn_mfma_f32_16x16x32_bf16(ah[rt], wl, acc2[rt][ct], 0, 0, 0);
        acc2[rt][ct] = __builtin_amdgcn_mfma_f32_16x16x32_bf16(al[rt], wh, acc2[rt][ct], 0, 0, 0);
      }
    }
  }

  // ---- final dot with W3 (relu on h2 in-register) ----
  const float w3a = W3[n0 + m16];
  const float w3b = W3[n0 + 16 + m16];
#pragma unroll
  for (int rt = 0; rt < 2; ++rt)
#pragma unroll
    for (int i = 0; i < 4; ++i) {
      float p = fmaxf(acc2[rt][0][i], 0.0f) * w3a + fmaxf(acc2[rt][1][i], 0.0f) * w3b;
      p += __shfl_xor(p, 1);
      p += __shfl_xor(p, 2);
      p += __shfl_xor(p, 4);
      p += __shfl_xor(p, 8);
      if (m16 == 0) sRed[rt * 16 + quad * 4 + i][wv] = p;
    }
  __syncthreads();
  if (tid < 32)
    out[row0 + tid] = sRed[tid][0] + sRed[tid][1] + sRed[tid][2] + sRed[tid][3] + b3[0];
}

}  // namespace

extern "C" void kernel_launch(void* const* d_in, const int* in_sizes, int n_in,
                              void* d_out, int out_size, void* d_ws, size_t ws_size,
                              hipStream_t stream) {
  const int* src_d2di  = (const int*)d_in[0];
  const int* dst_d2di  = (const int*)d_in[1];
  const int* src_di2dr = (const int*)d_in[2];
  const int* dst_di2dr = (const int*)d_in[3];
  const int* drug_idx  = (const int*)d_in[4];
  const int* dis_idx   = (const int*)d_in[5];
  const float* emb_drug = (const float*)d_in[6];
  const float* emb_dis  = (const float*)d_in[7];
  const float* Wl = (const float*)d_in[8];
  const float* bl = (const float*)d_in[9];
  const float* Wr = (const float*)d_in[10];
  const float* attn_Win  = (const float*)d_in[11];
  const float* attn_bin  = (const float*)d_in[12];
  const float* attn_Wout = (const float*)d_in[13];
  const float* attn_bout = (const float*)d_in[14];
  const float* W1 = (const float*)d_in[15];
  const float* b1 = (const float*)d_in[16];
  const float* W2 = (const float*)d_in[17];
  const float* b2 = (const float*)d_in[18];
  const float* W3 = (const float*)d_in[19];
  const float* b3 = (const float*)d_in[20];
  float* out = (float*)d_out;

  // ---- workspace carve (16B-aligned float units) ----
  float* ws = (float*)d_ws;
  size_t off = 0;
  auto carve = [&](size_t nfloats) {
    float* p = ws + off;
    off += (nfloats + 3) & ~(size_t)3;
    return p;
  };
  auto carveU = [&](size_t nush) { return (unsigned short*)carve((nush + 1) / 2); };

  // zeroed region (one memset): cnt/cursor ints + uchar flags + nctr
  int* cnt_dis     = (int*)carve(NDI);
  int* cnt_drug    = (int*)carve(NDR);
  int* cursor_dis  = (int*)carve(NDI);
  int* cursor_drug = (int*)carve(NDR);
  unsigned char* fb_dis  = (unsigned char*)carve((NDI + 3) / 4);
  unsigned char* fb_drug = (unsigned char*)carve((NDR + 3) / 4);
  unsigned char* fd_dis  = (unsigned char*)carve((NDI + 3) / 4);
  unsigned char* fd_drug = (unsigned char*)carve((NDR + 3) / 4);
  int* nctr        = (int*)carve(8);  // [0]=n_list_dis, [1]=n_list_drug
  const size_t zero_bytes = off * sizeof(float);
  // not zeroed
  int* off_dis   = (int*)carve(NDI);
  int* off_drug  = (int*)carve(NDR);
  int* list_dis  = (int*)carve(NDI);
  int* list_drug = (int*)carve(NDR);
  int* csr_d2di  = (int*)carve(NE);
  int* csr_di2dr = (int*)carve(NE);
  int* bsum_dis  = (int*)carve(256);
  int* bsum_drug = (int*)carve(256);

  // big split-bf16 buffers (NODE-indexed)
  unsigned short* aggh_dis  = carveU((size_t)NDI * HD);  // L0 mean agg
  unsigned short* aggl_dis  = carveU((size_t)NDI * HD);
  unsigned short* aggh_drug = carveU((size_t)NDR * HD);
  unsigned short* aggl_drug = carveU((size_t)NDR * HD);
  unsigned short* tgh_dis   = carveU((size_t)NDI * HD);  // L0 transformed (dis1_s0)
  unsigned short* tgl_dis   = carveU((size_t)NDI * HD);
  unsigned short* tgh_drug  = carveU((size_t)NDR * HD);  // L0 transformed (drug1_s1)
  unsigned short* tgl_drug  = carveU((size_t)NDR * HD);
  // batch-sized split buffers
  unsigned short* d1bh = carveU((size_t)NB * HD);  // drug1 (stack0) at batch rows
  unsigned short* d1bl = carveU((size_t)NB * HD);
  unsigned short* s1bh = carveU((size_t)NB * HD);  // dis1 (stack1) at batch rows
  unsigned short* s1bl = carveU((size_t)NB * HD);
  // weights (split, B-fragment swizzled)
  unsigned short* WLh = carveU(6 * 16384);
  unsigned short* WLl = carveU(6 * 16384);
  unsigned short* WRh = carveU(6 * 16384);
  unsigned short* WRl = carveU(6 * 16384);
  unsigned short* W2h = carveU(32768);
  unsigned short* W2l = carveU(32768);
  unsigned short* Amh = carveU(32768);
  unsigned short* Aml = carveU(32768);
  unsigned short* Bmh = carveU(32768);
  unsigned short* Bml = carveU(32768);
  // f32 small
  float* bc = carve(2 * HD);

  dim3 blk(256);
  const size_t WS = 16384;  // one 128x128 weight slot (elements)
  const int EB = (NE + 255) / 256;

  hipMemsetAsync(cnt_dis, 0, zero_bytes, stream);

  // weight prep (merged split + fold; independent of graph work)
  prep_weights<<<640, blk, 0, stream>>>(Wl, Wr, W2, WLh, WLl, WRh, WRl, W2h, W2l,
                                        W1, b1, attn_Win, attn_bin, attn_Wout, attn_bout,
                                        Amh, Aml, Bmh, Bml, bc);

  // demand marking (edge-parallel)
  batch_mark<<<(2 * NB + 255) / 256, blk, 0, stream>>>(drug_idx, dis_idx, fb_drug, fb_dis, fd_drug, fd_dis);
  edge_mark<<<dim3(EB, 2), blk, 0, stream>>>(src_d2di, dst_d2di, src_di2dr, dst_di2dr,
                                             fb_dis, fb_drug, fd_drug, fd_dis);

  // filtered degree counts; demand lists (1 atomic per 1024-thread block)
  count_f<<<dim3(EB, 2), blk, 0, stream>>>(dst_d2di, dst_di2dr, fd_dis, fd_drug, cnt_dis, cnt_drug);
  compact_list<<<dim3((NDR + 1023) / 1024, 2), dim3(1024), 0, stream>>>(
      fd_dis, NDI, list_dis, nctr + 0, fd_drug, NDR, list_drug, nctr + 1);

  // CSR offsets via deterministic 3-phase scan (filtered counts)
  scan1y<<<dim3((NDR + 1023) / 1024, 2), blk, 0, stream>>>(cnt_dis, NDI, off_dis, bsum_dis,
                                                           cnt_drug, NDR, off_drug, bsum_drug);
  scan2<<<2, blk, 0, stream>>>(bsum_dis, (NDI + 1023) / 1024, bsum_drug, (NDR + 1023) / 1024);
  scan3y<<<dim3((NDR + 255) / 256, 2), blk, 0, stream>>>(off_dis, NDI, bsum_dis, off_drug, NDR, bsum_drug);

  // filtered CSR scatter
  csr_f<<<dim3(EB, 2), blk, 0, stream>>>(src_d2di, dst_d2di, src_di2dr, dst_di2dr, NE,
                                         fd_dis, fd_drug,
                                         off_dis, cursor_dis, csr_d2di,
                                         off_drug, cursor_drug, csr_di2dr);

  // layer-0 mean aggregation at NODE rows (grid-stride, both directions)
  gather_f2s<<<dim3(1024, 2), blk, 0, stream>>>(
      emb_drug, csr_d2di, off_dis, cnt_dis, list_dis, nctr + 0, aggh_dis, aggl_dis,
      emb_dis, csr_di2dr, off_drug, cnt_drug, list_drug, nctr + 1, aggh_drug, aggl_drug);

  // all four L0 GEMMs in one grid-stride dispatch:
  //   a: dis1b (stack1, slot3) at batch rows; b: drug1b (stack0, slot1) at batch rows
  //   c: dis1_s0 (slot0) over list -> tg_dis (node rows)
  //   d: drug1_s1 (slot4) over list -> tg_drug (node rows)
  {
    L0Args z{};
    auto mk = [&](const unsigned short* X1h_, const unsigned short* X1l_, const float* x2_,
                  const int* rowNode_,
                  const unsigned short* Wah_, const unsigned short* Wal_,
                  const unsigned short* Wbh_, const unsigned short* Wbl_,
                  const float* bias_, const int* nDev,
                  unsigned short* Oh_, unsigned short* Ol_) {
      L0Args g = z;
      g.X1h = X1h_; g.X1l = X1l_; g.x2f32 = x2_;
      g.rowNode = rowNode_;
      g.Wah = Wah_; g.Wal = Wal_; g.Wbh = Wbh_; g.Wbl = Wbl_;
      g.bias = bias_; g.nRowsDev = nDev; g.Oh = Oh_; g.Ol = Ol_;
      return g;
    };
    L0Args a = mk(aggh_dis, aggl_dis, emb_dis, dis_idx,
                  WLh + 3 * WS, WLl + 3 * WS, WRh + 3 * WS, WRl + 3 * WS, bl + 4 * HD,
                  nullptr, s1bh, s1bl);
    L0Args b = mk(aggh_drug, aggl_drug, emb_drug, drug_idx,
                  WLh + 1 * WS, WLl + 1 * WS, WRh + 1 * WS, WRl + 1 * WS, bl + 1 * HD,
                  nullptr, d1bh, d1bl);
    L0Args c = mk(aggh_dis, aggl_dis, emb_dis, list_dis,
                  WLh + 0 * WS, WLl + 0 * WS, WRh + 0 * WS, WRl + 0 * WS, bl + 0 * HD,
                  nctr + 0, tgh_dis, tgl_dis);
    L0Args d = mk(aggh_drug, aggl_drug, emb_drug, list_drug,
                  WLh + 4 * WS, WLl + 4 * WS, WRh + 4 * WS, WRl + 4 * WS, bl + 5 * HD,
                  nctr + 1, tgh_drug, tgl_drug);
    l0_quad<<<2048, blk, 0, stream>>>(a, b, c, d);
  }

  // fused batch tail: L1 gather (LDS) + L1 pair (slots 2/5) -> MLP1 -> MLP2 -> dot(W3)
  tail_fused<<<NB / 32, blk, 0, stream>>>(
      tgh_dis, tgl_dis, tgh_drug, tgl_drug,
      drug_idx, dis_idx,
      csr_di2dr, off_drug, cnt_drug,
      csr_d2di, off_dis, cnt_dis,
      d1bh, d1bl, s1bh, s1bl,
      WLh + 2 * WS, WLl + 2 * WS, WRh + 2 * WS, WRl + 2 * WS,
      WLh + 5 * WS, WLl + 5 * WS, WRh + 5 * WS, WRl + 5 * WS,
      bl + 3 * HD, bl + 6 * HD,
      Amh, Aml, Bmh, Bml, bc, W2h, W2l, b2, W3, b3, out);

  (void)in_sizes; (void)n_in; (void)out_size; (void)ws_size;
}